// Round 2
// baseline (820.976 us; speedup 1.0000x reference)
//
#include <hip/hip_runtime.h>
#include <hip/hip_bf16.h>
#include <math.h>

// GAT x3 on N=100000 nodes, E=1600000 edges (+ self loops).
// Round 7: kill the sorted_dst scatter. scatter_kernel was the #1 dispatch
// (118us, 153MB WRITE_SIZE) because every edge did TWO random 4B stores
// (sorted_src + sorted_dst) -> 2 dirty 64B lines/edge. sorted_dst existed
// only for the edge-parallel ew4/ew6 weight kernels; those are now
// wave-per-destination-node (lanes stride the CSR segment), so dst data is
// a wave-uniform load and sorted_dst is gone. Halves scatter write traffic
// and removes the sortedd gathers from the ew kernels.

#define NN 100000
#define NE 1600000
#define NT (NE + NN)
#define FIN 50
#define HID 40
#define COUT 121

typedef __attribute__((ext_vector_type(8))) short bf16x8;
typedef __attribute__((ext_vector_type(4))) float f32x4;

__device__ __forceinline__ float lrelu(float x) { return fmaxf(x, 0.2f * x); }
__device__ __forceinline__ float elu1(float x)  { return x > 0.f ? x : __expf(x) - 1.f; }

// ---------------- CSR build ----------------
__global__ __launch_bounds__(256)
void deg_init_kernel(int* __restrict__ deg) {
    int i = blockIdx.x * 256 + threadIdx.x;
    if (i < NN) deg[i] = 1;  // self loop
}

__global__ __launch_bounds__(256)
void hist_kernel(const int* __restrict__ edst, int* __restrict__ deg) {
    int e = blockIdx.x * 256 + threadIdx.x;
    if (e < NE) atomicAdd(&deg[edst[e]], 1);
}

__global__ __launch_bounds__(256)
void scan_block_kernel(const int* __restrict__ deg, int* __restrict__ off,
                       int* __restrict__ bsum) {
    __shared__ int s[256];
    int t = threadIdx.x, b = blockIdx.x, i = b * 256 + t;
    int v = (i < NN) ? deg[i] : 0;
    s[t] = v; __syncthreads();
#pragma unroll
    for (int o = 1; o < 256; o <<= 1) {
        int x = (t >= o) ? s[t - o] : 0;
        __syncthreads();
        s[t] += x;
        __syncthreads();
    }
    if (i < NN) off[i] = s[t] - v;
    if (t == 255) bsum[b] = s[255];
}

__global__ __launch_bounds__(256)
void scan_bsum_kernel(const int* __restrict__ bsum, int* __restrict__ bscan, int nb) {
    __shared__ int s[256];
    int t = threadIdx.x;
    int carry = 0;
    int nc = (nb + 255) / 256;
    for (int c = 0; c < nc; c++) {
        int i = c * 256 + t;
        int v = (i < nb) ? bsum[i] : 0;
        s[t] = v; __syncthreads();
#pragma unroll
        for (int o = 1; o < 256; o <<= 1) {
            int x = (t >= o) ? s[t - o] : 0;
            __syncthreads();
            s[t] += x;
            __syncthreads();
        }
        if (i < nb) bscan[i] = carry + s[t] - v;
        carry += s[255];
        __syncthreads();
    }
}

__global__ __launch_bounds__(256)
void place_kernel(int* __restrict__ off, const int* __restrict__ bscan,
                  int* __restrict__ sorted_src, int* __restrict__ cursor) {
    int i = blockIdx.x * 256 + threadIdx.x;
    if (i == 0) off[NN] = NT;
    if (i < NN) {
        int o = off[i] + bscan[i >> 8];
        off[i] = o;
        sorted_src[o] = i;   // self loop first
        cursor[i] = o + 1;
    }
}

__global__ __launch_bounds__(256)
void scatter_kernel(const int* __restrict__ esrc, const int* __restrict__ edst,
                    int* __restrict__ cursor, int* __restrict__ sorted_src) {
    int e = blockIdx.x * 256 + threadIdx.x;
    if (e < NE) {
        int d = edst[e];
        int p = atomicAdd(&cursor[d], 1);
        sorted_src[p] = esrc[e];
    }
}

// ---------------- fold weight blocks ----------------
__global__ __launch_bounds__(256)
void fold_B12_kernel(const float* __restrict__ W, const float* __restrict__ lw,
                     const float* __restrict__ as_, const float* __restrict__ ad_,
                     float* __restrict__ B, int F) {
    int t = blockIdx.x * 256 + threadIdx.x;
    if (t >= F * 88) return;
    int f = t / 88, j = t - f * 88;
    float v = 0.f;
    if (j < 40) v = W[f * 40 + j];
    else if (j < 80) v = lw[f * 40 + (j - 40)];
    else if (j < 84) {
        int h = j - 80; float s = 0.f;
        for (int d = 0; d < 10; d++) s += W[f * 40 + h * 10 + d] * as_[h * 10 + d];
        v = s;
    } else {
        int h = j - 84; float s = 0.f;
        for (int d = 0; d < 10; d++) s += W[f * 40 + h * 10 + d] * ad_[h * 10 + d];
        v = s;
    }
    B[t] = v;
}

__global__ __launch_bounds__(256)
void fold_B3_kernel(const float* __restrict__ W3, const float* __restrict__ as3,
                    const float* __restrict__ ad3, float* __restrict__ B) {
    int t = blockIdx.x * 256 + threadIdx.x;
    if (t >= 40 * 12) return;
    int f = t / 12, k = t - f * 12;
    float s = 0.f;
    if (k < 6) {
        int h = k;
        for (int c = 0; c < COUT; c++) s += W3[f * 726 + h * COUT + c] * as3[h * COUT + c];
    } else {
        int h = k - 6;
        for (int c = 0; c < COUT; c++) s += W3[f * 726 + h * COUT + c] * ad3[h * COUT + c];
    }
    B[t] = s;
}

// Fold W3/lw3 into bf16 MFMA B-fragment order.
__global__ __launch_bounds__(256)
void fold_Bf_kernel(const float* __restrict__ W3, const float* __restrict__ lw3,
                    __hip_bfloat16* __restrict__ Bf) {
    int t = blockIdx.x * 256 + threadIdx.x;
    if (t >= 9 * 8 * 64 * 8) return;
    int j = t & 7, lane = (t >> 3) & 63, ct = (t >> 9) & 7, kt = t >> 12;
    int k = kt * 32 + (lane >> 4) * 8 + j;
    int c = ct * 16 + (lane & 15);
    float v = 0.f;
    if (c < COUT) {
        if (k < 240) {
            int h = k / 40, f = k - h * 40;
            v = W3[f * 726 + h * COUT + c];
        } else if (k < 280) {
            int f = k - 240;
            v = lw3[f * COUT + c];
        }
    }
    Bf[t] = __float2bfloat16(v);
}

// ---------------- fused feature GEMM for layers 1/2 ----------------
template <int F>
__global__ __launch_bounds__(256)
void feature12_kernel(const float* A, const float* __restrict__ B,
                      const float* __restrict__ bias, const float* __restrict__ lbias,
                      float* __restrict__ xw, float* agg,
                      float* __restrict__ asrc, float* __restrict__ adst) {
    int g0 = blockIdx.x * 256 + threadIdx.x;
    int r = g0 >> 2, p = g0 & 3;
    if (r >= NN) return;

    float a[F];
    if (F % 4 == 0) {
        const float4* A4 = reinterpret_cast<const float4*>(A + (size_t)r * F);
#pragma unroll
        for (int q = 0; q < F / 4; q++) {
            float4 v = A4[q];
            a[4 * q] = v.x; a[4 * q + 1] = v.y; a[4 * q + 2] = v.z; a[4 * q + 3] = v.w;
        }
    } else {
        const float2* A2 = reinterpret_cast<const float2*>(A + (size_t)r * F);
#pragma unroll
        for (int q = 0; q < F / 2; q++) {
            float2 v = A2[q];
            a[2 * q] = v.x; a[2 * q + 1] = v.y;
        }
        if (F & 1) a[F - 1] = A[(size_t)r * F + F - 1];
    }

    for (int g = p; g < 11; g += 4) {
        const int j0 = g * 8;
        float acc[8];
#pragma unroll
        for (int k = 0; k < 8; k++) acc[k] = 0.f;
#pragma unroll
        for (int f = 0; f < F; f++) {
            float av = a[f];
#pragma unroll
            for (int k = 0; k < 8; k++) acc[k] += av * B[f * 88 + j0 + k];
        }
        if (j0 < 40) {
            *reinterpret_cast<float4*>(xw + (size_t)r * 40 + j0) =
                make_float4(acc[0], acc[1], acc[2], acc[3]);
            *reinterpret_cast<float4*>(xw + (size_t)r * 40 + j0 + 4) =
                make_float4(acc[4], acc[5], acc[6], acc[7]);
        } else if (j0 < 80) {
            int j = j0 - 40;
#pragma unroll
            for (int k = 0; k < 8; k++) acc[k] += bias[j + k] + lbias[j + k];
            *reinterpret_cast<float4*>(agg + (size_t)r * 40 + j) =
                make_float4(acc[0], acc[1], acc[2], acc[3]);
            *reinterpret_cast<float4*>(agg + (size_t)r * 40 + j + 4) =
                make_float4(acc[4], acc[5], acc[6], acc[7]);
        } else {
            *reinterpret_cast<float4*>(asrc + (size_t)r * 8) =
                make_float4(acc[0], acc[1], acc[2], acc[3]);
            *reinterpret_cast<float4*>(adst + (size_t)r * 8) =
                make_float4(acc[4], acc[5], acc[6], acc[7]);
        }
    }
}

// ---------------- layer 3 scores + bf16 h2 copies (zb + packed hp) ----------
__global__ __launch_bounds__(256)
void feature3_kernel(const float* __restrict__ A, const float* __restrict__ B,
                     float* __restrict__ asrc, float* __restrict__ adst,
                     __hip_bfloat16* __restrict__ zb, __hip_bfloat16* __restrict__ hp) {
    int r = blockIdx.x * 256 + threadIdx.x;
    if (r >= NN) return;
    float a[40];
    const float4* A4 = reinterpret_cast<const float4*>(A + (size_t)r * 40);
#pragma unroll
    for (int q = 0; q < 10; q++) {
        float4 v = A4[q];
        a[4 * q] = v.x; a[4 * q + 1] = v.y; a[4 * q + 2] = v.z; a[4 * q + 3] = v.w;
    }
    __hip_bfloat16* zr = zb + (size_t)r * 288 + 240;
    __hip_bfloat16* hr = hp + (size_t)r * 40;
#pragma unroll
    for (int f = 0; f < 40; f++) {
        __hip_bfloat16 v = __float2bfloat16(a[f]);
        zr[f] = v;
        hr[f] = v;
    }
#pragma unroll
    for (int f = 40; f < 48; f++) zr[f] = __float2bfloat16(0.f);

    float acc[12];
#pragma unroll
    for (int k = 0; k < 12; k++) acc[k] = 0.f;
#pragma unroll
    for (int f = 0; f < 40; f++) {
        float av = a[f];
#pragma unroll
        for (int k = 0; k < 12; k++) acc[k] += av * B[f * 12 + k];
    }
    *reinterpret_cast<float4*>(asrc + (size_t)r * 8) = make_float4(acc[0], acc[1], acc[2], acc[3]);
    *reinterpret_cast<float2*>(asrc + (size_t)r * 8 + 4) = make_float2(acc[4], acc[5]);
    *reinterpret_cast<float4*>(adst + (size_t)r * 8) = make_float4(acc[6], acc[7], acc[8], acc[9]);
    *reinterpret_cast<float2*>(adst + (size_t)r * 8 + 4) = make_float2(acc[10], acc[11]);
}

// ---------------- per-node attention weights (wave per dst node) -----------
// Lanes stride the node's CSR segment. adst[d] is wave-uniform; only the
// asrc gather is random. w writes are contiguous within the segment.
__global__ __launch_bounds__(256)
void ew4_kernel(const int* __restrict__ off, const int* __restrict__ srt,
                const float* __restrict__ asrc, const float* __restrict__ adst,
                float* __restrict__ w4) {
    int wid = ((blockIdx.x * 256 + threadIdx.x) >> 6);
    int d = __builtin_amdgcn_readfirstlane(wid);
    if (d >= NN) return;
    int lane = threadIdx.x & 63;
    float4 b = *reinterpret_cast<const float4*>(adst + (size_t)d * 8);
    int jb = off[d], je = off[d + 1];
    for (int j = jb + lane; j < je; j += 64) {
        int s = srt[j];
        float4 a = *reinterpret_cast<const float4*>(asrc + (size_t)s * 8);
        float4 w;
        w.x = __expf(lrelu(a.x + b.x));
        w.y = __expf(lrelu(a.y + b.y));
        w.z = __expf(lrelu(a.z + b.z));
        w.w = __expf(lrelu(a.w + b.w));
        *reinterpret_cast<float4*>(w4 + (size_t)j * 4) = w;
    }
}

__global__ __launch_bounds__(256)
void ew6_kernel(const int* __restrict__ off, const int* __restrict__ srt,
                const float* __restrict__ asrc, const float* __restrict__ adst,
                float* __restrict__ w6) {
    int wid = ((blockIdx.x * 256 + threadIdx.x) >> 6);
    int d = __builtin_amdgcn_readfirstlane(wid);
    if (d >= NN) return;
    int lane = threadIdx.x & 63;
    float4 b0 = *reinterpret_cast<const float4*>(adst + (size_t)d * 8);
    float2 b1 = *reinterpret_cast<const float2*>(adst + (size_t)d * 8 + 4);
    int jb = off[d], je = off[d + 1];
    for (int j = jb + lane; j < je; j += 64) {
        int s = srt[j];
        float4 a0 = *reinterpret_cast<const float4*>(asrc + (size_t)s * 8);
        float2 a1 = *reinterpret_cast<const float2*>(asrc + (size_t)s * 8 + 4);
        float w0 = __expf(lrelu(a0.x + b0.x));
        float w1 = __expf(lrelu(a0.y + b0.y));
        float w2 = __expf(lrelu(a0.z + b0.z));
        float w3 = __expf(lrelu(a0.w + b0.w));
        float w4_ = __expf(lrelu(a1.x + b1.x));
        float w5 = __expf(lrelu(a1.y + b1.y));
        float* wp = w6 + (size_t)j * 6;
        *reinterpret_cast<float4*>(wp)     = make_float4(w0, w1, w2, w3);
        *reinterpret_cast<float2*>(wp + 4) = make_float2(w4_, w5);
    }
}

// ---------------- CSR aggregation, H=4 (layers 1/2), precomputed w, fused ELU
__global__ __launch_bounds__(256)
void agg4_csr_kernel(const int* __restrict__ off, const int* __restrict__ srt,
                     const float* __restrict__ w4,
                     const float* __restrict__ xw, float* agg) {
    int wid = ((blockIdx.x * 256 + threadIdx.x) >> 6);
    int d = __builtin_amdgcn_readfirstlane(wid);
    if (d >= NN) return;
    int lane = threadIdx.x & 63;
    bool act = lane < 40;
    int f = act ? lane : 0;
    int hh = f / 10;
    int jb = off[d], je = off[d + 1];
    float acc = 0.f, ds = 0.f;
    int j = jb;
    for (; j + 3 < je; j += 4) {
        int s0 = srt[j], s1 = srt[j + 1], s2 = srt[j + 2], s3 = srt[j + 3];
        float w0 = w4[(size_t)(j + 0) * 4 + hh];
        float w1 = w4[(size_t)(j + 1) * 4 + hh];
        float w2 = w4[(size_t)(j + 2) * 4 + hh];
        float w3 = w4[(size_t)(j + 3) * 4 + hh];
        float x0 = xw[(size_t)s0 * 40 + f], x1 = xw[(size_t)s1 * 40 + f];
        float x2 = xw[(size_t)s2 * 40 + f], x3 = xw[(size_t)s3 * 40 + f];
        acc += w0 * x0; acc += w1 * x1; acc += w2 * x2; acc += w3 * x3;
        ds += (w0 + w1) + (w2 + w3);
    }
    for (; j < je; ++j) {
        int s = srt[j];
        float w = w4[(size_t)j * 4 + hh];
        acc += w * xw[(size_t)s * 40 + f];
        ds += w;
    }
    if (act) {
        float v = agg[(size_t)d * 40 + f] + acc / ds;
        agg[(size_t)d * 40 + f] = elu1(v);   // ELU fused (layers 1/2 only)
    }
}

// ---------------- CSR aggregation, H=6 -> bf16 z, precomputed w, packed hp ---
__global__ __launch_bounds__(256)
void z6_csr_kernel(const int* __restrict__ off, const int* __restrict__ srt,
                   const float* __restrict__ w6,
                   const __hip_bfloat16* __restrict__ hp, __hip_bfloat16* zb) {
    int wid = ((blockIdx.x * 256 + threadIdx.x) >> 6);
    int d = __builtin_amdgcn_readfirstlane(wid);
    if (d >= NN) return;
    int lane = threadIdx.x & 63;
    bool act = lane < 40;
    int f = act ? lane : 0;
    int jb = off[d], je = off[d + 1];
    float acc[6], ds[6];
#pragma unroll
    for (int h = 0; h < 6; h++) { acc[h] = 0.f; ds[h] = 0.f; }
    int j = jb;
    for (; j + 1 < je; j += 2) {
        int s0 = srt[j], s1 = srt[j + 1];
        float hv0 = __bfloat162float(hp[(size_t)s0 * 40 + f]);
        float hv1 = __bfloat162float(hp[(size_t)s1 * 40 + f]);
        const float* wp = w6 + (size_t)j * 6;   // wave-uniform -> scalar loads
#pragma unroll
        for (int h = 0; h < 6; h++) {
            float w0 = wp[h], w1 = wp[6 + h];
            acc[h] += w0 * hv0; acc[h] += w1 * hv1;
            ds[h] += w0 + w1;
        }
    }
    for (; j < je; ++j) {
        int s = srt[j];
        float hv = __bfloat162float(hp[(size_t)s * 40 + f]);
        const float* wp = w6 + (size_t)j * 6;
#pragma unroll
        for (int h = 0; h < 6; h++) {
            acc[h] += wp[h] * hv;
            ds[h] += wp[h];
        }
    }
    if (act) {
#pragma unroll
        for (int h = 0; h < 6; h++)
            zb[(size_t)d * 288 + h * 40 + f] =
                __float2bfloat16(acc[h] / ds[h] * (1.0f / 6.0f));
    }
}

// ---------------- MFMA GEMM: out[100000x121] = A[100000x288]@B[288x128] + bias
__global__ __launch_bounds__(256)
void zgemm_mfma_kernel(const __hip_bfloat16* __restrict__ Ab,
                       const __hip_bfloat16* __restrict__ Bf,
                       const float* __restrict__ b3, const float* __restrict__ lb3,
                       float* __restrict__ out) {
    const int t = threadIdx.x;
    const int lane = t & 63, w = t >> 6;
    const int wr = w & 1, wc = w >> 1;
    const int n0 = blockIdx.x * 128;
    const short* As = (const short*)Ab;
    const short* Bs = (const short*)Bf;

    f32x4 acc[4][4];
#pragma unroll
    for (int i = 0; i < 4; i++)
#pragma unroll
        for (int j = 0; j < 4; j++) acc[i][j] = (f32x4){0.f, 0.f, 0.f, 0.f};

    const int arow = n0 + wr * 64 + (lane & 15);
    const int koff = (lane >> 4) * 8;

    for (int kk = 0; kk < 9; kk++) {
        bf16x8 af[4], bfr[4];
#pragma unroll
        for (int i = 0; i < 4; i++) {
            int r = arow + i * 16; if (r > NN - 1) r = NN - 1;
            af[i] = *(const bf16x8*)(As + (size_t)r * 288 + kk * 32 + koff);
        }
#pragma unroll
        for (int j = 0; j < 4; j++) {
            int ct = wc * 4 + j;
            bfr[j] = *(const bf16x8*)(Bs + (((size_t)kk * 8 + ct) * 64 + lane) * 8);
        }
#pragma unroll
        for (int i = 0; i < 4; i++)
#pragma unroll
            for (int j = 0; j < 4; j++)
                acc[i][j] = __builtin_amdgcn_mfma_f32_16x16x32_bf16(af[i], bfr[j], acc[i][j], 0, 0, 0);
    }

    const int c_base = wc * 64 + (lane & 15);
    const int r_quad = (lane >> 4) * 4;
#pragma unroll
    for (int j = 0; j < 4; j++) {
        int c = c_base + j * 16;
        if (c >= COUT) continue;
        float bias = b3[c] + lb3[c];
#pragma unroll
        for (int i = 0; i < 4; i++) {
            int nb = n0 + wr * 64 + i * 16 + r_quad;
#pragma unroll
            for (int q = 0; q < 4; q++) {
                int n = nb + q;
                if (n < NN) out[(size_t)n * COUT + c] = acc[i][j][q] + bias;
            }
        }
    }
}

extern "C" void kernel_launch(void* const* d_in, const int* in_sizes, int n_in,
                              void* d_out, int out_size, void* d_ws, size_t ws_size,
                              hipStream_t stream) {
    const float* x   = (const float*)d_in[0];
    const int*   ei  = (const int*)d_in[1];
    const float* W1  = (const float*)d_in[2];
    const float* as1 = (const float*)d_in[3];
    const float* ad1 = (const float*)d_in[4];
    const float* b1  = (const float*)d_in[5];
    const float* lw1 = (const float*)d_in[6];
    const float* lb1 = (const float*)d_in[7];
    const float* W2  = (const float*)d_in[8];
    const float* as2 = (const float*)d_in[9];
    const float* ad2 = (const float*)d_in[10];
    const float* b2  = (const float*)d_in[11];
    const float* lw2 = (const float*)d_in[12];
    const float* lb2 = (const float*)d_in[13];
    const float* W3  = (const float*)d_in[14];
    const float* as3 = (const float*)d_in[15];
    const float* ad3 = (const float*)d_in[16];
    const float* b3  = (const float*)d_in[17];
    const float* lw3 = (const float*)d_in[18];
    const float* lb3 = (const float*)d_in[19];
    float* out = (float*)d_out;
    float* ws  = (float*)d_ws;

    const int* esrc = ei;
    const int* edst = ei + NE;

    // ---- workspace layout (floats unless noted) ----
    // [0, 4M)        xw          (layers 1/2)   | hp (bf16, 2M floats) layer 3
    // [4M, 8M)       agg
    // [8M, 8.8M)     asrc
    // [8.8M, 9.6M)   adst
    // [9.6M, 9.608M) Bc
    // [9.608M, ...)  Bf (36864 bf16)
    // [9.628M, 24.028M) zb (bf16) layer 3       | w4 (NT*4 floats) layers 1/2
    // [24.028M, +ints) CSR: deg/off/cursor/bsum/bscan/sorted
    // [27.730M, 37.930M) w6 (NT*6 floats)
    float* xw   = ws;
    float* agg  = ws + 4000000;
    float* asrc = ws + 8000000;
    float* adst = ws + 8800000;
    float* Bc   = ws + 9600000;
    __hip_bfloat16* Bf = (__hip_bfloat16*)(ws + 9608000);
    __hip_bfloat16* zb = (__hip_bfloat16*)(ws + 9628000);
    float* w4 = ws + 9628000;                 // aliases zb (layers 1/2 only)
    __hip_bfloat16* hp = (__hip_bfloat16*)ws; // aliases xw (layer 3 only)
    int* ib     = (int*)(ws + 24028000);
    int* deg    = ib;
    int* off    = ib + 100352;
    int* cursor = ib + 200704;
    int* bsum   = ib + 300704;
    int* bscan  = ib + 301216;
    int* sorted = ib + 301728;
    float* w6   = ws + 27729728;

    const int nodeBlocks = (NN + 255) / 256;       // 391
    const int edgeBlocks = (NE + 255) / 256;       // 6250
    const int waveBlocks = NN / 4;                 // 25000
    const int featBlocks = (NN * 4 + 255) / 256;   // 1563

    // ---- CSR build ----
    deg_init_kernel<<<nodeBlocks, 256, 0, stream>>>(deg);
    hist_kernel<<<edgeBlocks, 256, 0, stream>>>(edst, deg);
    scan_block_kernel<<<nodeBlocks, 256, 0, stream>>>(deg, off, bsum);
    scan_bsum_kernel<<<1, 256, 0, stream>>>(bsum, bscan, nodeBlocks);
    place_kernel<<<nodeBlocks, 256, 0, stream>>>(off, bscan, sorted, cursor);
    scatter_kernel<<<edgeBlocks, 256, 0, stream>>>(esrc, edst, cursor, sorted);

    // ---- layer 1 ----
    fold_B12_kernel<<<(FIN * 88 + 255) / 256, 256, 0, stream>>>(W1, lw1, as1, ad1, Bc, FIN);
    feature12_kernel<FIN><<<featBlocks, 256, 0, stream>>>(x, Bc, b1, lb1, xw, agg, asrc, adst);
    ew4_kernel<<<waveBlocks, 256, 0, stream>>>(off, sorted, asrc, adst, w4);
    agg4_csr_kernel<<<waveBlocks, 256, 0, stream>>>(off, sorted, w4, xw, agg);

    // ---- layer 2 ----
    fold_B12_kernel<<<(HID * 88 + 255) / 256, 256, 0, stream>>>(W2, lw2, as2, ad2, Bc, HID);
    feature12_kernel<HID><<<featBlocks, 256, 0, stream>>>(agg, Bc, b2, lb2, xw, agg, asrc, adst);
    ew4_kernel<<<waveBlocks, 256, 0, stream>>>(off, sorted, asrc, adst, w4);
    agg4_csr_kernel<<<waveBlocks, 256, 0, stream>>>(off, sorted, w4, xw, agg);

    // ---- layer 3 ----
    fold_B3_kernel<<<(40 * 12 + 255) / 256, 256, 0, stream>>>(W3, as3, ad3, Bc);
    fold_Bf_kernel<<<(9 * 8 * 64 * 8 + 255) / 256, 256, 0, stream>>>(W3, lw3, Bf);
    feature3_kernel<<<nodeBlocks, 256, 0, stream>>>(agg, Bc, asrc, adst, zb, hp);
    ew6_kernel<<<waveBlocks, 256, 0, stream>>>(off, sorted, asrc, adst, w6);
    z6_csr_kernel<<<waveBlocks, 256, 0, stream>>>(off, sorted, w6, hp, zb);
    zgemm_mfma_kernel<<<(NN + 127) / 128, 256, 0, stream>>>(zb, Bf, b3, lb3, out);
}

// Round 3
// 707.683 us; speedup vs baseline: 1.1601x; 1.1601x over previous
//
#include <hip/hip_runtime.h>
#include <hip/hip_bf16.h>
#include <math.h>

// GAT x3 on N=100000 nodes, E=1600000 edges (+ self loops).
// Round 8: bucketed CSR build. The old hist (1.6M random global atomics) and
// scatter (1.6M random 4B stores, 105MB WRITE_SIZE, 16x line amplification
// from cross-XCD partial-dirty L2 thrash) are replaced by:
//   bin_count/bin_scan: 128-bucket histogram (782 dst nodes/bucket)
//   bin_place: block-exclusive chunk claiming + packed 4B records -> lines
//              written densely by ONE block -> written back once
//   bucket_deg: per-bucket LDS node histogram -> deg (no global atomics)
//   bucket_scatter: per-bucket LDS cursors, writes land in a block-exclusive
//              ~55KB CSR range (XCD-L2-local, written back once)
// Segment-internal edge order was already nondeterministic (atomic cursors),
// so numerics are unchanged in distribution.

#define NN 100000
#define NE 1600000
#define NT (NE + NN)
#define FIN 50
#define HID 40
#define COUT 121

#define NB 128           // buckets
#define NPB 782          // nodes per bucket (128*782 = 100096 >= NN)
#define EPB 8192         // edges per bin block

typedef __attribute__((ext_vector_type(8))) short bf16x8;
typedef __attribute__((ext_vector_type(4))) float f32x4;

__device__ __forceinline__ float lrelu(float x) { return fmaxf(x, 0.2f * x); }
__device__ __forceinline__ float elu1(float x)  { return x > 0.f ? x : __expf(x) - 1.f; }

// ---------------- bucketed CSR build ----------------
__global__ __launch_bounds__(256)
void zero_bcnt_kernel(int* __restrict__ bcnt) {
    int t = threadIdx.x;
    if (t < NB) bcnt[t] = 0;
}

__global__ __launch_bounds__(256)
void bin_count_kernel(const int* __restrict__ edst, int* __restrict__ bcnt) {
    __shared__ int h[NB];
    int t = threadIdx.x;
    if (t < NB) h[t] = 0;
    __syncthreads();
    int e0 = blockIdx.x * EPB;
    for (int q = 0; q < EPB; q += 256) {
        int e = e0 + q + t;
        if (e < NE) atomicAdd(&h[edst[e] / NPB], 1);
    }
    __syncthreads();
    if (t < NB && h[t]) atomicAdd(&bcnt[t], h[t]);
}

__global__ __launch_bounds__(256)
void bin_scan_kernel(const int* __restrict__ bcnt, int* __restrict__ boff,
                     int* __restrict__ bcur) {
    __shared__ int s[NB];
    int t = threadIdx.x;
    if (t < NB) s[t] = bcnt[t];
    __syncthreads();
    if (t == 0) {
        int run = 0;
        for (int i = 0; i < NB; i++) { int c = s[i]; s[i] = run; run += c; }
        boff[NB] = run;   // == NE
    }
    __syncthreads();
    if (t < NB) { boff[t] = s[t]; bcur[t] = s[t]; }
}

// Each block claims a contiguous chunk per bucket, then writes packed records
// src | (dst_in_bucket << 17) into its exclusive chunk (dense, short window).
__global__ __launch_bounds__(256)
void bin_place_kernel(const int* __restrict__ esrc, const int* __restrict__ edst,
                      int* __restrict__ bcur, int* __restrict__ ebuf) {
    __shared__ int h[NB], base[NB], lcur[NB];
    int t = threadIdx.x;
    if (t < NB) h[t] = 0;
    __syncthreads();
    int e0 = blockIdx.x * EPB;
    for (int q = 0; q < EPB; q += 256) {
        int e = e0 + q + t;
        if (e < NE) atomicAdd(&h[edst[e] / NPB], 1);
    }
    __syncthreads();
    if (t < NB) {
        int c = h[t];
        base[t] = c ? atomicAdd(&bcur[t], c) : 0;
        lcur[t] = 0;
    }
    __syncthreads();
    for (int q = 0; q < EPB; q += 256) {
        int e = e0 + q + t;
        if (e < NE) {
            int d = edst[e], s = esrc[e];
            int b = d / NPB;
            int r = atomicAdd(&lcur[b], 1);
            ebuf[base[b] + r] = s | ((d - b * NPB) << 17);
        }
    }
}

// One block per bucket: per-node degree via LDS histogram (replaces the old
// 1.6M-random-global-atomics hist_kernel).
__global__ __launch_bounds__(256)
void bucket_deg_kernel(const int* __restrict__ boff, const int* __restrict__ ebuf,
                       int* __restrict__ deg) {
    __shared__ int h[NPB];
    int b = blockIdx.x, t = threadIdx.x;
    for (int i = t; i < NPB; i += 256) h[i] = 0;
    __syncthreads();
    int jb = boff[b], je = boff[b + 1];
    for (int j = jb + t; j < je; j += 256) atomicAdd(&h[ebuf[j] >> 17], 1);
    __syncthreads();
    int n0 = b * NPB;
    for (int i = t; i < NPB; i += 256) {
        int n = n0 + i;
        if (n < NN) deg[n] = h[i] + 1;   // +1 self loop
    }
}

// One block per bucket: replay records with LDS cursors; sorted_src writes
// land in this block's exclusive CSR range (L2-local, written back once).
__global__ __launch_bounds__(256)
void bucket_scatter_kernel(const int* __restrict__ boff, const int* __restrict__ ebuf,
                           const int* __restrict__ off, int* __restrict__ sorted_src) {
    __shared__ int lcur[NPB];
    int b = blockIdx.x, t = threadIdx.x;
    int n0 = b * NPB;
    for (int i = t; i < NPB; i += 256) {
        int n = n0 + i;
        lcur[i] = (n < NN) ? off[n] + 1 : 0;   // +1: self loop occupies slot 0
    }
    __syncthreads();
    int jb = boff[b], je = boff[b + 1];
    for (int j = jb + t; j < je; j += 256) {
        int rec = ebuf[j];
        int p = atomicAdd(&lcur[rec >> 17], 1);
        sorted_src[p] = rec & 0x1FFFF;
    }
}

// ---------------- node-offset scan ----------------
__global__ __launch_bounds__(256)
void scan_block_kernel(const int* __restrict__ deg, int* __restrict__ off,
                       int* __restrict__ bsum) {
    __shared__ int s[256];
    int t = threadIdx.x, b = blockIdx.x, i = b * 256 + t;
    int v = (i < NN) ? deg[i] : 0;
    s[t] = v; __syncthreads();
#pragma unroll
    for (int o = 1; o < 256; o <<= 1) {
        int x = (t >= o) ? s[t - o] : 0;
        __syncthreads();
        s[t] += x;
        __syncthreads();
    }
    if (i < NN) off[i] = s[t] - v;
    if (t == 255) bsum[b] = s[255];
}

__global__ __launch_bounds__(256)
void scan_bsum_kernel(const int* __restrict__ bsum, int* __restrict__ bscan, int nb) {
    __shared__ int s[256];
    int t = threadIdx.x;
    int carry = 0;
    int nc = (nb + 255) / 256;
    for (int c = 0; c < nc; c++) {
        int i = c * 256 + t;
        int v = (i < nb) ? bsum[i] : 0;
        s[t] = v; __syncthreads();
#pragma unroll
        for (int o = 1; o < 256; o <<= 1) {
            int x = (t >= o) ? s[t - o] : 0;
            __syncthreads();
            s[t] += x;
            __syncthreads();
        }
        if (i < nb) bscan[i] = carry + s[t] - v;
        carry += s[255];
        __syncthreads();
    }
}

__global__ __launch_bounds__(256)
void place_kernel(int* __restrict__ off, const int* __restrict__ bscan,
                  int* __restrict__ sorted_src) {
    int i = blockIdx.x * 256 + threadIdx.x;
    if (i == 0) off[NN] = NT;
    if (i < NN) {
        int o = off[i] + bscan[i >> 8];
        off[i] = o;
        sorted_src[o] = i;   // self loop first
    }
}

// ---------------- fold weight blocks ----------------
__global__ __launch_bounds__(256)
void fold_B12_kernel(const float* __restrict__ W, const float* __restrict__ lw,
                     const float* __restrict__ as_, const float* __restrict__ ad_,
                     float* __restrict__ B, int F) {
    int t = blockIdx.x * 256 + threadIdx.x;
    if (t >= F * 88) return;
    int f = t / 88, j = t - f * 88;
    float v = 0.f;
    if (j < 40) v = W[f * 40 + j];
    else if (j < 80) v = lw[f * 40 + (j - 40)];
    else if (j < 84) {
        int h = j - 80; float s = 0.f;
        for (int d = 0; d < 10; d++) s += W[f * 40 + h * 10 + d] * as_[h * 10 + d];
        v = s;
    } else {
        int h = j - 84; float s = 0.f;
        for (int d = 0; d < 10; d++) s += W[f * 40 + h * 10 + d] * ad_[h * 10 + d];
        v = s;
    }
    B[t] = v;
}

__global__ __launch_bounds__(256)
void fold_B3_kernel(const float* __restrict__ W3, const float* __restrict__ as3,
                    const float* __restrict__ ad3, float* __restrict__ B) {
    int t = blockIdx.x * 256 + threadIdx.x;
    if (t >= 40 * 12) return;
    int f = t / 12, k = t - f * 12;
    float s = 0.f;
    if (k < 6) {
        int h = k;
        for (int c = 0; c < COUT; c++) s += W3[f * 726 + h * COUT + c] * as3[h * COUT + c];
    } else {
        int h = k - 6;
        for (int c = 0; c < COUT; c++) s += W3[f * 726 + h * COUT + c] * ad3[h * COUT + c];
    }
    B[t] = s;
}

// Fold W3/lw3 into bf16 MFMA B-fragment order.
__global__ __launch_bounds__(256)
void fold_Bf_kernel(const float* __restrict__ W3, const float* __restrict__ lw3,
                    __hip_bfloat16* __restrict__ Bf) {
    int t = blockIdx.x * 256 + threadIdx.x;
    if (t >= 9 * 8 * 64 * 8) return;
    int j = t & 7, lane = (t >> 3) & 63, ct = (t >> 9) & 7, kt = t >> 12;
    int k = kt * 32 + (lane >> 4) * 8 + j;
    int c = ct * 16 + (lane & 15);
    float v = 0.f;
    if (c < COUT) {
        if (k < 240) {
            int h = k / 40, f = k - h * 40;
            v = W3[f * 726 + h * COUT + c];
        } else if (k < 280) {
            int f = k - 240;
            v = lw3[f * COUT + c];
        }
    }
    Bf[t] = __float2bfloat16(v);
}

// ---------------- fused feature GEMM for layers 1/2 ----------------
template <int F>
__global__ __launch_bounds__(256)
void feature12_kernel(const float* A, const float* __restrict__ B,
                      const float* __restrict__ bias, const float* __restrict__ lbias,
                      float* __restrict__ xw, float* agg,
                      float* __restrict__ asrc, float* __restrict__ adst) {
    int g0 = blockIdx.x * 256 + threadIdx.x;
    int r = g0 >> 2, p = g0 & 3;
    if (r >= NN) return;

    float a[F];
    if (F % 4 == 0) {
        const float4* A4 = reinterpret_cast<const float4*>(A + (size_t)r * F);
#pragma unroll
        for (int q = 0; q < F / 4; q++) {
            float4 v = A4[q];
            a[4 * q] = v.x; a[4 * q + 1] = v.y; a[4 * q + 2] = v.z; a[4 * q + 3] = v.w;
        }
    } else {
        const float2* A2 = reinterpret_cast<const float2*>(A + (size_t)r * F);
#pragma unroll
        for (int q = 0; q < F / 2; q++) {
            float2 v = A2[q];
            a[2 * q] = v.x; a[2 * q + 1] = v.y;
        }
        if (F & 1) a[F - 1] = A[(size_t)r * F + F - 1];
    }

    for (int g = p; g < 11; g += 4) {
        const int j0 = g * 8;
        float acc[8];
#pragma unroll
        for (int k = 0; k < 8; k++) acc[k] = 0.f;
#pragma unroll
        for (int f = 0; f < F; f++) {
            float av = a[f];
#pragma unroll
            for (int k = 0; k < 8; k++) acc[k] += av * B[f * 88 + j0 + k];
        }
        if (j0 < 40) {
            *reinterpret_cast<float4*>(xw + (size_t)r * 40 + j0) =
                make_float4(acc[0], acc[1], acc[2], acc[3]);
            *reinterpret_cast<float4*>(xw + (size_t)r * 40 + j0 + 4) =
                make_float4(acc[4], acc[5], acc[6], acc[7]);
        } else if (j0 < 80) {
            int j = j0 - 40;
#pragma unroll
            for (int k = 0; k < 8; k++) acc[k] += bias[j + k] + lbias[j + k];
            *reinterpret_cast<float4*>(agg + (size_t)r * 40 + j) =
                make_float4(acc[0], acc[1], acc[2], acc[3]);
            *reinterpret_cast<float4*>(agg + (size_t)r * 40 + j + 4) =
                make_float4(acc[4], acc[5], acc[6], acc[7]);
        } else {
            *reinterpret_cast<float4*>(asrc + (size_t)r * 8) =
                make_float4(acc[0], acc[1], acc[2], acc[3]);
            *reinterpret_cast<float4*>(adst + (size_t)r * 8) =
                make_float4(acc[4], acc[5], acc[6], acc[7]);
        }
    }
}

// ---------------- layer 3 scores + bf16 h2 copies (zb + packed hp) ----------
__global__ __launch_bounds__(256)
void feature3_kernel(const float* __restrict__ A, const float* __restrict__ B,
                     float* __restrict__ asrc, float* __restrict__ adst,
                     __hip_bfloat16* __restrict__ zb, __hip_bfloat16* __restrict__ hp) {
    int r = blockIdx.x * 256 + threadIdx.x;
    if (r >= NN) return;
    float a[40];
    const float4* A4 = reinterpret_cast<const float4*>(A + (size_t)r * 40);
#pragma unroll
    for (int q = 0; q < 10; q++) {
        float4 v = A4[q];
        a[4 * q] = v.x; a[4 * q + 1] = v.y; a[4 * q + 2] = v.z; a[4 * q + 3] = v.w;
    }
    __hip_bfloat16* zr = zb + (size_t)r * 288 + 240;
    __hip_bfloat16* hr = hp + (size_t)r * 40;
#pragma unroll
    for (int f = 0; f < 40; f++) {
        __hip_bfloat16 v = __float2bfloat16(a[f]);
        zr[f] = v;
        hr[f] = v;
    }
#pragma unroll
    for (int f = 40; f < 48; f++) zr[f] = __float2bfloat16(0.f);

    float acc[12];
#pragma unroll
    for (int k = 0; k < 12; k++) acc[k] = 0.f;
#pragma unroll
    for (int f = 0; f < 40; f++) {
        float av = a[f];
#pragma unroll
        for (int k = 0; k < 12; k++) acc[k] += av * B[f * 12 + k];
    }
    *reinterpret_cast<float4*>(asrc + (size_t)r * 8) = make_float4(acc[0], acc[1], acc[2], acc[3]);
    *reinterpret_cast<float2*>(asrc + (size_t)r * 8 + 4) = make_float2(acc[4], acc[5]);
    *reinterpret_cast<float4*>(adst + (size_t)r * 8) = make_float4(acc[6], acc[7], acc[8], acc[9]);
    *reinterpret_cast<float2*>(adst + (size_t)r * 8 + 4) = make_float2(acc[10], acc[11]);
}

// ---------------- per-node attention weights (wave per dst node) -----------
__global__ __launch_bounds__(256)
void ew4_kernel(const int* __restrict__ off, const int* __restrict__ srt,
                const float* __restrict__ asrc, const float* __restrict__ adst,
                float* __restrict__ w4) {
    int wid = ((blockIdx.x * 256 + threadIdx.x) >> 6);
    int d = __builtin_amdgcn_readfirstlane(wid);
    if (d >= NN) return;
    int lane = threadIdx.x & 63;
    float4 b = *reinterpret_cast<const float4*>(adst + (size_t)d * 8);
    int jb = off[d], je = off[d + 1];
    for (int j = jb + lane; j < je; j += 64) {
        int s = srt[j];
        float4 a = *reinterpret_cast<const float4*>(asrc + (size_t)s * 8);
        float4 w;
        w.x = __expf(lrelu(a.x + b.x));
        w.y = __expf(lrelu(a.y + b.y));
        w.z = __expf(lrelu(a.z + b.z));
        w.w = __expf(lrelu(a.w + b.w));
        *reinterpret_cast<float4*>(w4 + (size_t)j * 4) = w;
    }
}

__global__ __launch_bounds__(256)
void ew6_kernel(const int* __restrict__ off, const int* __restrict__ srt,
                const float* __restrict__ asrc, const float* __restrict__ adst,
                float* __restrict__ w6) {
    int wid = ((blockIdx.x * 256 + threadIdx.x) >> 6);
    int d = __builtin_amdgcn_readfirstlane(wid);
    if (d >= NN) return;
    int lane = threadIdx.x & 63;
    float4 b0 = *reinterpret_cast<const float4*>(adst + (size_t)d * 8);
    float2 b1 = *reinterpret_cast<const float2*>(adst + (size_t)d * 8 + 4);
    int jb = off[d], je = off[d + 1];
    for (int j = jb + lane; j < je; j += 64) {
        int s = srt[j];
        float4 a0 = *reinterpret_cast<const float4*>(asrc + (size_t)s * 8);
        float2 a1 = *reinterpret_cast<const float2*>(asrc + (size_t)s * 8 + 4);
        float w0 = __expf(lrelu(a0.x + b0.x));
        float w1 = __expf(lrelu(a0.y + b0.y));
        float w2 = __expf(lrelu(a0.z + b0.z));
        float w3 = __expf(lrelu(a0.w + b0.w));
        float w4_ = __expf(lrelu(a1.x + b1.x));
        float w5 = __expf(lrelu(a1.y + b1.y));
        float* wp = w6 + (size_t)j * 6;
        *reinterpret_cast<float4*>(wp)     = make_float4(w0, w1, w2, w3);
        *reinterpret_cast<float2*>(wp + 4) = make_float2(w4_, w5);
    }
}

// ---------------- CSR aggregation, H=4 (layers 1/2), precomputed w, fused ELU
__global__ __launch_bounds__(256)
void agg4_csr_kernel(const int* __restrict__ off, const int* __restrict__ srt,
                     const float* __restrict__ w4,
                     const float* __restrict__ xw, float* agg) {
    int wid = ((blockIdx.x * 256 + threadIdx.x) >> 6);
    int d = __builtin_amdgcn_readfirstlane(wid);
    if (d >= NN) return;
    int lane = threadIdx.x & 63;
    bool act = lane < 40;
    int f = act ? lane : 0;
    int hh = f / 10;
    int jb = off[d], je = off[d + 1];
    float acc = 0.f, ds = 0.f;
    int j = jb;
    for (; j + 3 < je; j += 4) {
        int s0 = srt[j], s1 = srt[j + 1], s2 = srt[j + 2], s3 = srt[j + 3];
        float w0 = w4[(size_t)(j + 0) * 4 + hh];
        float w1 = w4[(size_t)(j + 1) * 4 + hh];
        float w2 = w4[(size_t)(j + 2) * 4 + hh];
        float w3 = w4[(size_t)(j + 3) * 4 + hh];
        float x0 = xw[(size_t)s0 * 40 + f], x1 = xw[(size_t)s1 * 40 + f];
        float x2 = xw[(size_t)s2 * 40 + f], x3 = xw[(size_t)s3 * 40 + f];
        acc += w0 * x0; acc += w1 * x1; acc += w2 * x2; acc += w3 * x3;
        ds += (w0 + w1) + (w2 + w3);
    }
    for (; j < je; ++j) {
        int s = srt[j];
        float w = w4[(size_t)j * 4 + hh];
        acc += w * xw[(size_t)s * 40 + f];
        ds += w;
    }
    if (act) {
        float v = agg[(size_t)d * 40 + f] + acc / ds;
        agg[(size_t)d * 40 + f] = elu1(v);   // ELU fused (layers 1/2 only)
    }
}

// ---------------- CSR aggregation, H=6 -> bf16 z, precomputed w, packed hp ---
__global__ __launch_bounds__(256)
void z6_csr_kernel(const int* __restrict__ off, const int* __restrict__ srt,
                   const float* __restrict__ w6,
                   const __hip_bfloat16* __restrict__ hp, __hip_bfloat16* zb) {
    int wid = ((blockIdx.x * 256 + threadIdx.x) >> 6);
    int d = __builtin_amdgcn_readfirstlane(wid);
    if (d >= NN) return;
    int lane = threadIdx.x & 63;
    bool act = lane < 40;
    int f = act ? lane : 0;
    int jb = off[d], je = off[d + 1];
    float acc[6], ds[6];
#pragma unroll
    for (int h = 0; h < 6; h++) { acc[h] = 0.f; ds[h] = 0.f; }
    int j = jb;
    for (; j + 1 < je; j += 2) {
        int s0 = srt[j], s1 = srt[j + 1];
        float hv0 = __bfloat162float(hp[(size_t)s0 * 40 + f]);
        float hv1 = __bfloat162float(hp[(size_t)s1 * 40 + f]);
        const float* wp = w6 + (size_t)j * 6;   // wave-uniform -> scalar loads
#pragma unroll
        for (int h = 0; h < 6; h++) {
            float w0 = wp[h], w1 = wp[6 + h];
            acc[h] += w0 * hv0; acc[h] += w1 * hv1;
            ds[h] += w0 + w1;
        }
    }
    for (; j < je; ++j) {
        int s = srt[j];
        float hv = __bfloat162float(hp[(size_t)s * 40 + f]);
        const float* wp = w6 + (size_t)j * 6;
#pragma unroll
        for (int h = 0; h < 6; h++) {
            acc[h] += wp[h] * hv;
            ds[h] += wp[h];
        }
    }
    if (act) {
#pragma unroll
        for (int h = 0; h < 6; h++)
            zb[(size_t)d * 288 + h * 40 + f] =
                __float2bfloat16(acc[h] / ds[h] * (1.0f / 6.0f));
    }
}

// ---------------- MFMA GEMM: out[100000x121] = A[100000x288]@B[288x128] + bias
__global__ __launch_bounds__(256)
void zgemm_mfma_kernel(const __hip_bfloat16* __restrict__ Ab,
                       const __hip_bfloat16* __restrict__ Bf,
                       const float* __restrict__ b3, const float* __restrict__ lb3,
                       float* __restrict__ out) {
    const int t = threadIdx.x;
    const int lane = t & 63, w = t >> 6;
    const int wr = w & 1, wc = w >> 1;
    const int n0 = blockIdx.x * 128;
    const short* As = (const short*)Ab;
    const short* Bs = (const short*)Bf;

    f32x4 acc[4][4];
#pragma unroll
    for (int i = 0; i < 4; i++)
#pragma unroll
        for (int j = 0; j < 4; j++) acc[i][j] = (f32x4){0.f, 0.f, 0.f, 0.f};

    const int arow = n0 + wr * 64 + (lane & 15);
    const int koff = (lane >> 4) * 8;

    for (int kk = 0; kk < 9; kk++) {
        bf16x8 af[4], bfr[4];
#pragma unroll
        for (int i = 0; i < 4; i++) {
            int r = arow + i * 16; if (r > NN - 1) r = NN - 1;
            af[i] = *(const bf16x8*)(As + (size_t)r * 288 + kk * 32 + koff);
        }
#pragma unroll
        for (int j = 0; j < 4; j++) {
            int ct = wc * 4 + j;
            bfr[j] = *(const bf16x8*)(Bs + (((size_t)kk * 8 + ct) * 64 + lane) * 8);
        }
#pragma unroll
        for (int i = 0; i < 4; i++)
#pragma unroll
            for (int j = 0; j < 4; j++)
                acc[i][j] = __builtin_amdgcn_mfma_f32_16x16x32_bf16(af[i], bfr[j], acc[i][j], 0, 0, 0);
    }

    const int c_base = wc * 64 + (lane & 15);
    const int r_quad = (lane >> 4) * 4;
#pragma unroll
    for (int j = 0; j < 4; j++) {
        int c = c_base + j * 16;
        if (c >= COUT) continue;
        float bias = b3[c] + lb3[c];
#pragma unroll
        for (int i = 0; i < 4; i++) {
            int nb = n0 + wr * 64 + i * 16 + r_quad;
#pragma unroll
            for (int q = 0; q < 4; q++) {
                int n = nb + q;
                if (n < NN) out[(size_t)n * COUT + c] = acc[i][j][q] + bias;
            }
        }
    }
}

extern "C" void kernel_launch(void* const* d_in, const int* in_sizes, int n_in,
                              void* d_out, int out_size, void* d_ws, size_t ws_size,
                              hipStream_t stream) {
    const float* x   = (const float*)d_in[0];
    const int*   ei  = (const int*)d_in[1];
    const float* W1  = (const float*)d_in[2];
    const float* as1 = (const float*)d_in[3];
    const float* ad1 = (const float*)d_in[4];
    const float* b1  = (const float*)d_in[5];
    const float* lw1 = (const float*)d_in[6];
    const float* lb1 = (const float*)d_in[7];
    const float* W2  = (const float*)d_in[8];
    const float* as2 = (const float*)d_in[9];
    const float* ad2 = (const float*)d_in[10];
    const float* b2  = (const float*)d_in[11];
    const float* lw2 = (const float*)d_in[12];
    const float* lb2 = (const float*)d_in[13];
    const float* W3  = (const float*)d_in[14];
    const float* as3 = (const float*)d_in[15];
    const float* ad3 = (const float*)d_in[16];
    const float* b3  = (const float*)d_in[17];
    const float* lw3 = (const float*)d_in[18];
    const float* lb3 = (const float*)d_in[19];
    float* out = (float*)d_out;
    float* ws  = (float*)d_ws;

    const int* esrc = ei;
    const int* edst = ei + NE;

    // ---- workspace layout (floats unless noted) ----
    // [0, 4M)        xw          (layers 1/2)   | hp (bf16, 2M floats) layer 3
    // [4M, 8M)       agg
    // [8M, 8.8M)     asrc
    // [8.8M, 9.6M)   adst
    // [9.6M, 9.608M) Bc
    // [9.608M, ...)  Bf (36864 bf16)
    // [9.628M, 24.028M) zb (bf16) layer 3       | w4 (NT*4 floats) layers 1/2
    // [24.028M, +3,701,728 ints) CSR ints (see below)
    // [27.730M, 37.930M) w6 (NT*6 floats)
    float* xw   = ws;
    float* agg  = ws + 4000000;
    float* asrc = ws + 8000000;
    float* adst = ws + 8800000;
    float* Bc   = ws + 9600000;
    __hip_bfloat16* Bf = (__hip_bfloat16*)(ws + 9608000);
    __hip_bfloat16* zb = (__hip_bfloat16*)(ws + 9628000);
    float* w4 = ws + 9628000;                 // aliases zb (layers 1/2 only)
    __hip_bfloat16* hp = (__hip_bfloat16*)ws; // aliases xw (layer 3 only)
    int* ib     = (int*)(ws + 24028000);
    int* deg    = ib;                 // 100,352
    int* off    = ib + 100352;        // 100,001 (+pad)
    int* bcnt   = ib + 200704;        // 128
    int* boff   = ib + 200832;        // 129
    int* bcur   = ib + 200992;        // 128
    int* bsum   = ib + 300704;        // 512
    int* bscan  = ib + 301216;        // 512
    int* sorted = ib + 301728;        // 1,700,000 -> ends 2,001,728
    int* ebuf   = ib + 2001728;       // 1,600,000 -> ends 3,601,728
    float* w6   = ws + 27729728;

    const int nodeBlocks = (NN + 255) / 256;       // 391
    const int binBlocks  = (NE + EPB - 1) / EPB;   // 196
    const int waveBlocks = NN / 4;                 // 25000
    const int featBlocks = (NN * 4 + 255) / 256;   // 1563

    // ---- bucketed CSR build ----
    zero_bcnt_kernel<<<1, 256, 0, stream>>>(bcnt);
    bin_count_kernel<<<binBlocks, 256, 0, stream>>>(edst, bcnt);
    bin_scan_kernel<<<1, 256, 0, stream>>>(bcnt, boff, bcur);
    bin_place_kernel<<<binBlocks, 256, 0, stream>>>(esrc, edst, bcur, ebuf);
    bucket_deg_kernel<<<NB, 256, 0, stream>>>(boff, ebuf, deg);
    scan_block_kernel<<<nodeBlocks, 256, 0, stream>>>(deg, off, bsum);
    scan_bsum_kernel<<<1, 256, 0, stream>>>(bsum, bscan, nodeBlocks);
    place_kernel<<<nodeBlocks, 256, 0, stream>>>(off, bscan, sorted);
    bucket_scatter_kernel<<<NB, 256, 0, stream>>>(boff, ebuf, off, sorted);

    // ---- layer 1 ----
    fold_B12_kernel<<<(FIN * 88 + 255) / 256, 256, 0, stream>>>(W1, lw1, as1, ad1, Bc, FIN);
    feature12_kernel<FIN><<<featBlocks, 256, 0, stream>>>(x, Bc, b1, lb1, xw, agg, asrc, adst);
    ew4_kernel<<<waveBlocks, 256, 0, stream>>>(off, sorted, asrc, adst, w4);
    agg4_csr_kernel<<<waveBlocks, 256, 0, stream>>>(off, sorted, w4, xw, agg);

    // ---- layer 2 ----
    fold_B12_kernel<<<(HID * 88 + 255) / 256, 256, 0, stream>>>(W2, lw2, as2, ad2, Bc, HID);
    feature12_kernel<HID><<<featBlocks, 256, 0, stream>>>(agg, Bc, b2, lb2, xw, agg, asrc, adst);
    ew4_kernel<<<waveBlocks, 256, 0, stream>>>(off, sorted, asrc, adst, w4);
    agg4_csr_kernel<<<waveBlocks, 256, 0, stream>>>(off, sorted, w4, xw, agg);

    // ---- layer 3 ----
    fold_B3_kernel<<<(40 * 12 + 255) / 256, 256, 0, stream>>>(W3, as3, ad3, Bc);
    fold_Bf_kernel<<<(9 * 8 * 64 * 8 + 255) / 256, 256, 0, stream>>>(W3, lw3, Bf);
    feature3_kernel<<<nodeBlocks, 256, 0, stream>>>(agg, Bc, asrc, adst, zb, hp);
    ew6_kernel<<<waveBlocks, 256, 0, stream>>>(off, sorted, asrc, adst, w6);
    z6_csr_kernel<<<waveBlocks, 256, 0, stream>>>(off, sorted, w6, hp, zb);
    zgemm_mfma_kernel<<<(NN + 127) / 128, 256, 0, stream>>>(zb, Bf, b3, lb3, out);
}

// Round 4
// 606.742 us; speedup vs baseline: 1.3531x; 1.1664x over previous
//
#include <hip/hip_runtime.h>
#include <hip/hip_bf16.h>
#include <math.h>

// GAT x3 on N=100000 nodes, E=1600000 edges (+ self loops).
// Round 9: feature12 was latency-bound (114us, VALUBusy 7.6%, HBM 5.8%) on
// per-lane global B loads in the FMA chain. Restructured: block = 64 rows x
// 4 waves, p = wave index (not tid&3), B panel staged in LDS; inner-loop B
// reads are wave-uniform LDS broadcasts (no VMEM latency, no conflicts).
// Work partition / FMA order / stores unchanged -> identical numerics.
// (Round 8: bucketed CSR build; round 6/7: hoisted edge weights, ew kernels
// wave-per-dst-node so sorted_dst isn't needed.)

#define NN 100000
#define NE 1600000
#define NT (NE + NN)
#define FIN 50
#define HID 40
#define COUT 121

#define NB 128           // buckets
#define NPB 782          // nodes per bucket (128*782 = 100096 >= NN)
#define EPB 8192         // edges per bin block

typedef __attribute__((ext_vector_type(8))) short bf16x8;
typedef __attribute__((ext_vector_type(4))) float f32x4;

__device__ __forceinline__ float lrelu(float x) { return fmaxf(x, 0.2f * x); }
__device__ __forceinline__ float elu1(float x)  { return x > 0.f ? x : __expf(x) - 1.f; }

// ---------------- bucketed CSR build ----------------
__global__ __launch_bounds__(256)
void zero_bcnt_kernel(int* __restrict__ bcnt) {
    int t = threadIdx.x;
    if (t < NB) bcnt[t] = 0;
}

__global__ __launch_bounds__(256)
void bin_count_kernel(const int* __restrict__ edst, int* __restrict__ bcnt) {
    __shared__ int h[NB];
    int t = threadIdx.x;
    if (t < NB) h[t] = 0;
    __syncthreads();
    int e0 = blockIdx.x * EPB;
    for (int q = 0; q < EPB; q += 256) {
        int e = e0 + q + t;
        if (e < NE) atomicAdd(&h[edst[e] / NPB], 1);
    }
    __syncthreads();
    if (t < NB && h[t]) atomicAdd(&bcnt[t], h[t]);
}

__global__ __launch_bounds__(256)
void bin_scan_kernel(const int* __restrict__ bcnt, int* __restrict__ boff,
                     int* __restrict__ bcur) {
    __shared__ int s[NB];
    int t = threadIdx.x;
    if (t < NB) s[t] = bcnt[t];
    __syncthreads();
    if (t == 0) {
        int run = 0;
        for (int i = 0; i < NB; i++) { int c = s[i]; s[i] = run; run += c; }
        boff[NB] = run;   // == NE
    }
    __syncthreads();
    if (t < NB) { boff[t] = s[t]; bcur[t] = s[t]; }
}

// Each block claims a contiguous chunk per bucket, then writes packed records
// src | (dst_in_bucket << 17) into its exclusive chunk (dense, short window).
__global__ __launch_bounds__(256)
void bin_place_kernel(const int* __restrict__ esrc, const int* __restrict__ edst,
                      int* __restrict__ bcur, int* __restrict__ ebuf) {
    __shared__ int h[NB], base[NB], lcur[NB];
    int t = threadIdx.x;
    if (t < NB) h[t] = 0;
    __syncthreads();
    int e0 = blockIdx.x * EPB;
    for (int q = 0; q < EPB; q += 256) {
        int e = e0 + q + t;
        if (e < NE) atomicAdd(&h[edst[e] / NPB], 1);
    }
    __syncthreads();
    if (t < NB) {
        int c = h[t];
        base[t] = c ? atomicAdd(&bcur[t], c) : 0;
        lcur[t] = 0;
    }
    __syncthreads();
    for (int q = 0; q < EPB; q += 256) {
        int e = e0 + q + t;
        if (e < NE) {
            int d = edst[e], s = esrc[e];
            int b = d / NPB;
            int r = atomicAdd(&lcur[b], 1);
            ebuf[base[b] + r] = s | ((d - b * NPB) << 17);
        }
    }
}

// One block per bucket: per-node degree via LDS histogram.
__global__ __launch_bounds__(256)
void bucket_deg_kernel(const int* __restrict__ boff, const int* __restrict__ ebuf,
                       int* __restrict__ deg) {
    __shared__ int h[NPB];
    int b = blockIdx.x, t = threadIdx.x;
    for (int i = t; i < NPB; i += 256) h[i] = 0;
    __syncthreads();
    int jb = boff[b], je = boff[b + 1];
    for (int j = jb + t; j < je; j += 256) atomicAdd(&h[ebuf[j] >> 17], 1);
    __syncthreads();
    int n0 = b * NPB;
    for (int i = t; i < NPB; i += 256) {
        int n = n0 + i;
        if (n < NN) deg[n] = h[i] + 1;   // +1 self loop
    }
}

// One block per bucket: replay records with LDS cursors; sorted_src writes
// land in this block's exclusive CSR range (L2-local, written back once).
__global__ __launch_bounds__(256)
void bucket_scatter_kernel(const int* __restrict__ boff, const int* __restrict__ ebuf,
                           const int* __restrict__ off, int* __restrict__ sorted_src) {
    __shared__ int lcur[NPB];
    int b = blockIdx.x, t = threadIdx.x;
    int n0 = b * NPB;
    for (int i = t; i < NPB; i += 256) {
        int n = n0 + i;
        lcur[i] = (n < NN) ? off[n] + 1 : 0;   // +1: self loop occupies slot 0
    }
    __syncthreads();
    int jb = boff[b], je = boff[b + 1];
    for (int j = jb + t; j < je; j += 256) {
        int rec = ebuf[j];
        int p = atomicAdd(&lcur[rec >> 17], 1);
        sorted_src[p] = rec & 0x1FFFF;
    }
}

// ---------------- node-offset scan ----------------
__global__ __launch_bounds__(256)
void scan_block_kernel(const int* __restrict__ deg, int* __restrict__ off,
                       int* __restrict__ bsum) {
    __shared__ int s[256];
    int t = threadIdx.x, b = blockIdx.x, i = b * 256 + t;
    int v = (i < NN) ? deg[i] : 0;
    s[t] = v; __syncthreads();
#pragma unroll
    for (int o = 1; o < 256; o <<= 1) {
        int x = (t >= o) ? s[t - o] : 0;
        __syncthreads();
        s[t] += x;
        __syncthreads();
    }
    if (i < NN) off[i] = s[t] - v;
    if (t == 255) bsum[b] = s[255];
}

__global__ __launch_bounds__(256)
void scan_bsum_kernel(const int* __restrict__ bsum, int* __restrict__ bscan, int nb) {
    __shared__ int s[256];
    int t = threadIdx.x;
    int carry = 0;
    int nc = (nb + 255) / 256;
    for (int c = 0; c < nc; c++) {
        int i = c * 256 + t;
        int v = (i < nb) ? bsum[i] : 0;
        s[t] = v; __syncthreads();
#pragma unroll
        for (int o = 1; o < 256; o <<= 1) {
            int x = (t >= o) ? s[t - o] : 0;
            __syncthreads();
            s[t] += x;
            __syncthreads();
        }
        if (i < nb) bscan[i] = carry + s[t] - v;
        carry += s[255];
        __syncthreads();
    }
}

__global__ __launch_bounds__(256)
void place_kernel(int* __restrict__ off, const int* __restrict__ bscan,
                  int* __restrict__ sorted_src) {
    int i = blockIdx.x * 256 + threadIdx.x;
    if (i == 0) off[NN] = NT;
    if (i < NN) {
        int o = off[i] + bscan[i >> 8];
        off[i] = o;
        sorted_src[o] = i;   // self loop first
    }
}

// ---------------- fold weight blocks ----------------
__global__ __launch_bounds__(256)
void fold_B12_kernel(const float* __restrict__ W, const float* __restrict__ lw,
                     const float* __restrict__ as_, const float* __restrict__ ad_,
                     float* __restrict__ B, int F) {
    int t = blockIdx.x * 256 + threadIdx.x;
    if (t >= F * 88) return;
    int f = t / 88, j = t - f * 88;
    float v = 0.f;
    if (j < 40) v = W[f * 40 + j];
    else if (j < 80) v = lw[f * 40 + (j - 40)];
    else if (j < 84) {
        int h = j - 80; float s = 0.f;
        for (int d = 0; d < 10; d++) s += W[f * 40 + h * 10 + d] * as_[h * 10 + d];
        v = s;
    } else {
        int h = j - 84; float s = 0.f;
        for (int d = 0; d < 10; d++) s += W[f * 40 + h * 10 + d] * ad_[h * 10 + d];
        v = s;
    }
    B[t] = v;
}

__global__ __launch_bounds__(256)
void fold_B3_kernel(const float* __restrict__ W3, const float* __restrict__ as3,
                    const float* __restrict__ ad3, float* __restrict__ B) {
    int t = blockIdx.x * 256 + threadIdx.x;
    if (t >= 40 * 12) return;
    int f = t / 12, k = t - f * 12;
    float s = 0.f;
    if (k < 6) {
        int h = k;
        for (int c = 0; c < COUT; c++) s += W3[f * 726 + h * COUT + c] * as3[h * COUT + c];
    } else {
        int h = k - 6;
        for (int c = 0; c < COUT; c++) s += W3[f * 726 + h * COUT + c] * ad3[h * COUT + c];
    }
    B[t] = s;
}

// Fold W3/lw3 into bf16 MFMA B-fragment order.
__global__ __launch_bounds__(256)
void fold_Bf_kernel(const float* __restrict__ W3, const float* __restrict__ lw3,
                    __hip_bfloat16* __restrict__ Bf) {
    int t = blockIdx.x * 256 + threadIdx.x;
    if (t >= 9 * 8 * 64 * 8) return;
    int j = t & 7, lane = (t >> 3) & 63, ct = (t >> 9) & 7, kt = t >> 12;
    int k = kt * 32 + (lane >> 4) * 8 + j;
    int c = ct * 16 + (lane & 15);
    float v = 0.f;
    if (c < COUT) {
        if (k < 240) {
            int h = k / 40, f = k - h * 40;
            v = W3[f * 726 + h * COUT + c];
        } else if (k < 280) {
            int f = k - 240;
            v = lw3[f * COUT + c];
        }
    }
    Bf[t] = __float2bfloat16(v);
}

// ---------------- fused feature GEMM for layers 1/2 ----------------
// Block = 64 rows x 4 waves. p = wave index; wave p handles column-groups
// g = p, p+4, p+8 for the block's rows. B panel lives in LDS; inner-loop B
// reads are wave-uniform (j0, f uniform) -> HW broadcast, no VMEM latency.
template <int F>
__global__ __launch_bounds__(256)
void feature12_kernel(const float* __restrict__ A, const float* __restrict__ B,
                      const float* __restrict__ bias, const float* __restrict__ lbias,
                      float* __restrict__ xw, float* __restrict__ agg,
                      float* __restrict__ asrc, float* __restrict__ adst) {
    __shared__ float sB[F * 88];
    const int t = threadIdx.x;
    for (int i = t; i < F * 88; i += 256) sB[i] = B[i];

    const int lane = t & 63;
    const int p = __builtin_amdgcn_readfirstlane(t >> 6);
    const int r = blockIdx.x * 64 + lane;
    const bool valid = r < NN;
    const int rr = valid ? r : NN - 1;

    float a[F];
    if (F % 4 == 0) {
        const float4* A4 = reinterpret_cast<const float4*>(A + (size_t)rr * F);
#pragma unroll
        for (int q = 0; q < F / 4; q++) {
            float4 v = A4[q];
            a[4 * q] = v.x; a[4 * q + 1] = v.y; a[4 * q + 2] = v.z; a[4 * q + 3] = v.w;
        }
    } else {
        const float2* A2 = reinterpret_cast<const float2*>(A + (size_t)rr * F);
#pragma unroll
        for (int q = 0; q < F / 2; q++) {
            float2 v = A2[q];
            a[2 * q] = v.x; a[2 * q + 1] = v.y;
        }
        if (F & 1) a[F - 1] = A[(size_t)rr * F + F - 1];
    }
    __syncthreads();

    for (int g = p; g < 11; g += 4) {
        const int j0 = g * 8;
        float acc[8];
#pragma unroll
        for (int k = 0; k < 8; k++) acc[k] = 0.f;
#pragma unroll
        for (int f = 0; f < F; f++) {
            float av = a[f];
            float4 b0 = *reinterpret_cast<const float4*>(&sB[f * 88 + j0]);
            float4 b1 = *reinterpret_cast<const float4*>(&sB[f * 88 + j0 + 4]);
            acc[0] += av * b0.x; acc[1] += av * b0.y;
            acc[2] += av * b0.z; acc[3] += av * b0.w;
            acc[4] += av * b1.x; acc[5] += av * b1.y;
            acc[6] += av * b1.z; acc[7] += av * b1.w;
        }
        if (!valid) continue;
        if (j0 < 40) {
            *reinterpret_cast<float4*>(xw + (size_t)r * 40 + j0) =
                make_float4(acc[0], acc[1], acc[2], acc[3]);
            *reinterpret_cast<float4*>(xw + (size_t)r * 40 + j0 + 4) =
                make_float4(acc[4], acc[5], acc[6], acc[7]);
        } else if (j0 < 80) {
            int j = j0 - 40;
#pragma unroll
            for (int k = 0; k < 8; k++) acc[k] += bias[j + k] + lbias[j + k];
            *reinterpret_cast<float4*>(agg + (size_t)r * 40 + j) =
                make_float4(acc[0], acc[1], acc[2], acc[3]);
            *reinterpret_cast<float4*>(agg + (size_t)r * 40 + j + 4) =
                make_float4(acc[4], acc[5], acc[6], acc[7]);
        } else {
            *reinterpret_cast<float4*>(asrc + (size_t)r * 8) =
                make_float4(acc[0], acc[1], acc[2], acc[3]);
            *reinterpret_cast<float4*>(adst + (size_t)r * 8) =
                make_float4(acc[4], acc[5], acc[6], acc[7]);
        }
    }
}

// ---------------- layer 3 scores + bf16 h2 copies (zb + packed hp) ----------
__global__ __launch_bounds__(256)
void feature3_kernel(const float* __restrict__ A, const float* __restrict__ B,
                     float* __restrict__ asrc, float* __restrict__ adst,
                     __hip_bfloat16* __restrict__ zb, __hip_bfloat16* __restrict__ hp) {
    int r = blockIdx.x * 256 + threadIdx.x;
    if (r >= NN) return;
    float a[40];
    const float4* A4 = reinterpret_cast<const float4*>(A + (size_t)r * 40);
#pragma unroll
    for (int q = 0; q < 10; q++) {
        float4 v = A4[q];
        a[4 * q] = v.x; a[4 * q + 1] = v.y; a[4 * q + 2] = v.z; a[4 * q + 3] = v.w;
    }
    __hip_bfloat16* zr = zb + (size_t)r * 288 + 240;
    __hip_bfloat16* hr = hp + (size_t)r * 40;
#pragma unroll
    for (int f = 0; f < 40; f++) {
        __hip_bfloat16 v = __float2bfloat16(a[f]);
        zr[f] = v;
        hr[f] = v;
    }
#pragma unroll
    for (int f = 40; f < 48; f++) zr[f] = __float2bfloat16(0.f);

    float acc[12];
#pragma unroll
    for (int k = 0; k < 12; k++) acc[k] = 0.f;
#pragma unroll
    for (int f = 0; f < 40; f++) {
        float av = a[f];
#pragma unroll
        for (int k = 0; k < 12; k++) acc[k] += av * B[f * 12 + k];
    }
    *reinterpret_cast<float4*>(asrc + (size_t)r * 8) = make_float4(acc[0], acc[1], acc[2], acc[3]);
    *reinterpret_cast<float2*>(asrc + (size_t)r * 8 + 4) = make_float2(acc[4], acc[5]);
    *reinterpret_cast<float4*>(adst + (size_t)r * 8) = make_float4(acc[6], acc[7], acc[8], acc[9]);
    *reinterpret_cast<float2*>(adst + (size_t)r * 8 + 4) = make_float2(acc[10], acc[11]);
}

// ---------------- per-node attention weights (wave per dst node) -----------
__global__ __launch_bounds__(256)
void ew4_kernel(const int* __restrict__ off, const int* __restrict__ srt,
                const float* __restrict__ asrc, const float* __restrict__ adst,
                float* __restrict__ w4) {
    int wid = ((blockIdx.x * 256 + threadIdx.x) >> 6);
    int d = __builtin_amdgcn_readfirstlane(wid);
    if (d >= NN) return;
    int lane = threadIdx.x & 63;
    float4 b = *reinterpret_cast<const float4*>(adst + (size_t)d * 8);
    int jb = off[d], je = off[d + 1];
    for (int j = jb + lane; j < je; j += 64) {
        int s = srt[j];
        float4 a = *reinterpret_cast<const float4*>(asrc + (size_t)s * 8);
        float4 w;
        w.x = __expf(lrelu(a.x + b.x));
        w.y = __expf(lrelu(a.y + b.y));
        w.z = __expf(lrelu(a.z + b.z));
        w.w = __expf(lrelu(a.w + b.w));
        *reinterpret_cast<float4*>(w4 + (size_t)j * 4) = w;
    }
}

__global__ __launch_bounds__(256)
void ew6_kernel(const int* __restrict__ off, const int* __restrict__ srt,
                const float* __restrict__ asrc, const float* __restrict__ adst,
                float* __restrict__ w6) {
    int wid = ((blockIdx.x * 256 + threadIdx.x) >> 6);
    int d = __builtin_amdgcn_readfirstlane(wid);
    if (d >= NN) return;
    int lane = threadIdx.x & 63;
    float4 b0 = *reinterpret_cast<const float4*>(adst + (size_t)d * 8);
    float2 b1 = *reinterpret_cast<const float2*>(adst + (size_t)d * 8 + 4);
    int jb = off[d], je = off[d + 1];
    for (int j = jb + lane; j < je; j += 64) {
        int s = srt[j];
        float4 a0 = *reinterpret_cast<const float4*>(asrc + (size_t)s * 8);
        float2 a1 = *reinterpret_cast<const float2*>(asrc + (size_t)s * 8 + 4);
        float w0 = __expf(lrelu(a0.x + b0.x));
        float w1 = __expf(lrelu(a0.y + b0.y));
        float w2 = __expf(lrelu(a0.z + b0.z));
        float w3 = __expf(lrelu(a0.w + b0.w));
        float w4_ = __expf(lrelu(a1.x + b1.x));
        float w5 = __expf(lrelu(a1.y + b1.y));
        float* wp = w6 + (size_t)j * 6;
        *reinterpret_cast<float4*>(wp)     = make_float4(w0, w1, w2, w3);
        *reinterpret_cast<float2*>(wp + 4) = make_float2(w4_, w5);
    }
}

// ---------------- CSR aggregation, H=4 (layers 1/2), precomputed w, fused ELU
__global__ __launch_bounds__(256)
void agg4_csr_kernel(const int* __restrict__ off, const int* __restrict__ srt,
                     const float* __restrict__ w4,
                     const float* __restrict__ xw, float* agg) {
    int wid = ((blockIdx.x * 256 + threadIdx.x) >> 6);
    int d = __builtin_amdgcn_readfirstlane(wid);
    if (d >= NN) return;
    int lane = threadIdx.x & 63;
    bool act = lane < 40;
    int f = act ? lane : 0;
    int hh = f / 10;
    int jb = off[d], je = off[d + 1];
    float acc = 0.f, ds = 0.f;
    int j = jb;
    for (; j + 3 < je; j += 4) {
        int s0 = srt[j], s1 = srt[j + 1], s2 = srt[j + 2], s3 = srt[j + 3];
        float w0 = w4[(size_t)(j + 0) * 4 + hh];
        float w1 = w4[(size_t)(j + 1) * 4 + hh];
        float w2 = w4[(size_t)(j + 2) * 4 + hh];
        float w3 = w4[(size_t)(j + 3) * 4 + hh];
        float x0 = xw[(size_t)s0 * 40 + f], x1 = xw[(size_t)s1 * 40 + f];
        float x2 = xw[(size_t)s2 * 40 + f], x3 = xw[(size_t)s3 * 40 + f];
        acc += w0 * x0; acc += w1 * x1; acc += w2 * x2; acc += w3 * x3;
        ds += (w0 + w1) + (w2 + w3);
    }
    for (; j < je; ++j) {
        int s = srt[j];
        float w = w4[(size_t)j * 4 + hh];
        acc += w * xw[(size_t)s * 40 + f];
        ds += w;
    }
    if (act) {
        float v = agg[(size_t)d * 40 + f] + acc / ds;
        agg[(size_t)d * 40 + f] = elu1(v);   // ELU fused (layers 1/2 only)
    }
}

// ---------------- CSR aggregation, H=6 -> bf16 z, precomputed w, packed hp ---
__global__ __launch_bounds__(256)
void z6_csr_kernel(const int* __restrict__ off, const int* __restrict__ srt,
                   const float* __restrict__ w6,
                   const __hip_bfloat16* __restrict__ hp, __hip_bfloat16* zb) {
    int wid = ((blockIdx.x * 256 + threadIdx.x) >> 6);
    int d = __builtin_amdgcn_readfirstlane(wid);
    if (d >= NN) return;
    int lane = threadIdx.x & 63;
    bool act = lane < 40;
    int f = act ? lane : 0;
    int jb = off[d], je = off[d + 1];
    float acc[6], ds[6];
#pragma unroll
    for (int h = 0; h < 6; h++) { acc[h] = 0.f; ds[h] = 0.f; }
    int j = jb;
    for (; j + 1 < je; j += 2) {
        int s0 = srt[j], s1 = srt[j + 1];
        float hv0 = __bfloat162float(hp[(size_t)s0 * 40 + f]);
        float hv1 = __bfloat162float(hp[(size_t)s1 * 40 + f]);
        const float* wp = w6 + (size_t)j * 6;   // wave-uniform -> scalar loads
#pragma unroll
        for (int h = 0; h < 6; h++) {
            float w0 = wp[h], w1 = wp[6 + h];
            acc[h] += w0 * hv0; acc[h] += w1 * hv1;
            ds[h] += w0 + w1;
        }
    }
    for (; j < je; ++j) {
        int s = srt[j];
        float hv = __bfloat162float(hp[(size_t)s * 40 + f]);
        const float* wp = w6 + (size_t)j * 6;
#pragma unroll
        for (int h = 0; h < 6; h++) {
            acc[h] += wp[h] * hv;
            ds[h] += wp[h];
        }
    }
    if (act) {
#pragma unroll
        for (int h = 0; h < 6; h++)
            zb[(size_t)d * 288 + h * 40 + f] =
                __float2bfloat16(acc[h] / ds[h] * (1.0f / 6.0f));
    }
}

// ---------------- MFMA GEMM: out[100000x121] = A[100000x288]@B[288x128] + bias
__global__ __launch_bounds__(256)
void zgemm_mfma_kernel(const __hip_bfloat16* __restrict__ Ab,
                       const __hip_bfloat16* __restrict__ Bf,
                       const float* __restrict__ b3, const float* __restrict__ lb3,
                       float* __restrict__ out) {
    const int t = threadIdx.x;
    const int lane = t & 63, w = t >> 6;
    const int wr = w & 1, wc = w >> 1;
    const int n0 = blockIdx.x * 128;
    const short* As = (const short*)Ab;
    const short* Bs = (const short*)Bf;

    f32x4 acc[4][4];
#pragma unroll
    for (int i = 0; i < 4; i++)
#pragma unroll
        for (int j = 0; j < 4; j++) acc[i][j] = (f32x4){0.f, 0.f, 0.f, 0.f};

    const int arow = n0 + wr * 64 + (lane & 15);
    const int koff = (lane >> 4) * 8;

    for (int kk = 0; kk < 9; kk++) {
        bf16x8 af[4], bfr[4];
#pragma unroll
        for (int i = 0; i < 4; i++) {
            int r = arow + i * 16; if (r > NN - 1) r = NN - 1;
            af[i] = *(const bf16x8*)(As + (size_t)r * 288 + kk * 32 + koff);
        }
#pragma unroll
        for (int j = 0; j < 4; j++) {
            int ct = wc * 4 + j;
            bfr[j] = *(const bf16x8*)(Bs + (((size_t)kk * 8 + ct) * 64 + lane) * 8);
        }
#pragma unroll
        for (int i = 0; i < 4; i++)
#pragma unroll
            for (int j = 0; j < 4; j++)
                acc[i][j] = __builtin_amdgcn_mfma_f32_16x16x32_bf16(af[i], bfr[j], acc[i][j], 0, 0, 0);
    }

    const int c_base = wc * 64 + (lane & 15);
    const int r_quad = (lane >> 4) * 4;
#pragma unroll
    for (int j = 0; j < 4; j++) {
        int c = c_base + j * 16;
        if (c >= COUT) continue;
        float bias = b3[c] + lb3[c];
#pragma unroll
        for (int i = 0; i < 4; i++) {
            int nb = n0 + wr * 64 + i * 16 + r_quad;
#pragma unroll
            for (int q = 0; q < 4; q++) {
                int n = nb + q;
                if (n < NN) out[(size_t)n * COUT + c] = acc[i][j][q] + bias;
            }
        }
    }
}

extern "C" void kernel_launch(void* const* d_in, const int* in_sizes, int n_in,
                              void* d_out, int out_size, void* d_ws, size_t ws_size,
                              hipStream_t stream) {
    const float* x   = (const float*)d_in[0];
    const int*   ei  = (const int*)d_in[1];
    const float* W1  = (const float*)d_in[2];
    const float* as1 = (const float*)d_in[3];
    const float* ad1 = (const float*)d_in[4];
    const float* b1  = (const float*)d_in[5];
    const float* lw1 = (const float*)d_in[6];
    const float* lb1 = (const float*)d_in[7];
    const float* W2  = (const float*)d_in[8];
    const float* as2 = (const float*)d_in[9];
    const float* ad2 = (const float*)d_in[10];
    const float* b2  = (const float*)d_in[11];
    const float* lw2 = (const float*)d_in[12];
    const float* lb2 = (const float*)d_in[13];
    const float* W3  = (const float*)d_in[14];
    const float* as3 = (const float*)d_in[15];
    const float* ad3 = (const float*)d_in[16];
    const float* b3  = (const float*)d_in[17];
    const float* lw3 = (const float*)d_in[18];
    const float* lb3 = (const float*)d_in[19];
    float* out = (float*)d_out;
    float* ws  = (float*)d_ws;

    const int* esrc = ei;
    const int* edst = ei + NE;

    // ---- workspace layout (floats unless noted) ----
    float* xw   = ws;
    float* agg  = ws + 4000000;
    float* asrc = ws + 8000000;
    float* adst = ws + 8800000;
    float* Bc   = ws + 9600000;
    __hip_bfloat16* Bf = (__hip_bfloat16*)(ws + 9608000);
    __hip_bfloat16* zb = (__hip_bfloat16*)(ws + 9628000);
    float* w4 = ws + 9628000;                 // aliases zb (layers 1/2 only)
    __hip_bfloat16* hp = (__hip_bfloat16*)ws; // aliases xw (layer 3 only)
    int* ib     = (int*)(ws + 24028000);
    int* deg    = ib;                 // 100,352
    int* off    = ib + 100352;        // 100,001 (+pad)
    int* bcnt   = ib + 200704;        // 128
    int* boff   = ib + 200832;        // 129
    int* bcur   = ib + 200992;        // 128
    int* bsum   = ib + 300704;        // 512
    int* bscan  = ib + 301216;        // 512
    int* sorted = ib + 301728;        // 1,700,000 -> ends 2,001,728
    int* ebuf   = ib + 2001728;       // 1,600,000 -> ends 3,601,728
    float* w6   = ws + 27729728;

    const int nodeBlocks = (NN + 255) / 256;       // 391
    const int binBlocks  = (NE + EPB - 1) / EPB;   // 196
    const int waveBlocks = NN / 4;                 // 25000
    const int featBlocks = (NN + 63) / 64;         // 1563 (64 rows/block)

    // ---- bucketed CSR build ----
    zero_bcnt_kernel<<<1, 256, 0, stream>>>(bcnt);
    bin_count_kernel<<<binBlocks, 256, 0, stream>>>(edst, bcnt);
    bin_scan_kernel<<<1, 256, 0, stream>>>(bcnt, boff, bcur);
    bin_place_kernel<<<binBlocks, 256, 0, stream>>>(esrc, edst, bcur, ebuf);
    bucket_deg_kernel<<<NB, 256, 0, stream>>>(boff, ebuf, deg);
    scan_block_kernel<<<nodeBlocks, 256, 0, stream>>>(deg, off, bsum);
    scan_bsum_kernel<<<1, 256, 0, stream>>>(bsum, bscan, nodeBlocks);
    place_kernel<<<nodeBlocks, 256, 0, stream>>>(off, bscan, sorted);
    bucket_scatter_kernel<<<NB, 256, 0, stream>>>(boff, ebuf, off, sorted);

    // ---- layer 1 ----
    fold_B12_kernel<<<(FIN * 88 + 255) / 256, 256, 0, stream>>>(W1, lw1, as1, ad1, Bc, FIN);
    feature12_kernel<FIN><<<featBlocks, 256, 0, stream>>>(x, Bc, b1, lb1, xw, agg, asrc, adst);
    ew4_kernel<<<waveBlocks, 256, 0, stream>>>(off, sorted, asrc, adst, w4);
    agg4_csr_kernel<<<waveBlocks, 256, 0, stream>>>(off, sorted, w4, xw, agg);

    // ---- layer 2 ----
    fold_B12_kernel<<<(HID * 88 + 255) / 256, 256, 0, stream>>>(W2, lw2, as2, ad2, Bc, HID);
    feature12_kernel<HID><<<featBlocks, 256, 0, stream>>>(agg, Bc, b2, lb2, xw, agg, asrc, adst);
    ew4_kernel<<<waveBlocks, 256, 0, stream>>>(off, sorted, asrc, adst, w4);
    agg4_csr_kernel<<<waveBlocks, 256, 0, stream>>>(off, sorted, w4, xw, agg);

    // ---- layer 3 ----
    fold_B3_kernel<<<(40 * 12 + 255) / 256, 256, 0, stream>>>(W3, as3, ad3, Bc);
    fold_Bf_kernel<<<(9 * 8 * 64 * 8 + 255) / 256, 256, 0, stream>>>(W3, lw3, Bf);
    feature3_kernel<<<nodeBlocks, 256, 0, stream>>>(agg, Bc, asrc, adst, zb, hp);
    ew6_kernel<<<waveBlocks, 256, 0, stream>>>(off, sorted, asrc, adst, w6);
    z6_csr_kernel<<<waveBlocks, 256, 0, stream>>>(off, sorted, w6, hp, zb);
    zgemm_mfma_kernel<<<(NN + 127) / 128, 256, 0, stream>>>(zb, Bf, b3, lb3, out);
}

// Round 5
// 546.936 us; speedup vs baseline: 1.5010x; 1.1093x over previous
//
#include <hip/hip_runtime.h>
#include <hip/hip_bf16.h>
#include <math.h>

// GAT x3 on N=100000 nodes, E=1600000 edges (+ self loops).
// Round 10: fuse edge-weight computation back into the aggregation kernels
// WITHOUT the round-5 64x lane redundancy. Per wave (one dst node), segments
// are processed in chunks of 64: phase A = one lane per edge computes the
// exp(lrelu(...)) weights (once) + stashes src id into a private LDS slice;
// phase B = the FMA loop reads w/s via wave-uniform LDS broadcast. This
// deletes ew4/ew6 kernels and the 27/27/41 MB w4/w6 HBM round-trips.
// FMA order identical to round 9 -> bit-identical numerics.
// (R9: feature12 LDS-B panel; R8: bucketed CSR build; R6/7: weight hoist.)

#define NN 100000
#define NE 1600000
#define NT (NE + NN)
#define FIN 50
#define HID 40
#define COUT 121

#define NB 128           // buckets
#define NPB 782          // nodes per bucket (128*782 = 100096 >= NN)
#define EPB 8192         // edges per bin block

typedef __attribute__((ext_vector_type(8))) short bf16x8;
typedef __attribute__((ext_vector_type(4))) float f32x4;

__device__ __forceinline__ float lrelu(float x) { return fmaxf(x, 0.2f * x); }
__device__ __forceinline__ float elu1(float x)  { return x > 0.f ? x : __expf(x) - 1.f; }

// ---------------- bucketed CSR build ----------------
__global__ __launch_bounds__(256)
void zero_bcnt_kernel(int* __restrict__ bcnt) {
    int t = threadIdx.x;
    if (t < NB) bcnt[t] = 0;
}

__global__ __launch_bounds__(256)
void bin_count_kernel(const int* __restrict__ edst, int* __restrict__ bcnt) {
    __shared__ int h[NB];
    int t = threadIdx.x;
    if (t < NB) h[t] = 0;
    __syncthreads();
    int e0 = blockIdx.x * EPB;
    for (int q = 0; q < EPB; q += 256) {
        int e = e0 + q + t;
        if (e < NE) atomicAdd(&h[edst[e] / NPB], 1);
    }
    __syncthreads();
    if (t < NB && h[t]) atomicAdd(&bcnt[t], h[t]);
}

__global__ __launch_bounds__(256)
void bin_scan_kernel(const int* __restrict__ bcnt, int* __restrict__ boff,
                     int* __restrict__ bcur) {
    __shared__ int s[NB];
    int t = threadIdx.x;
    if (t < NB) s[t] = bcnt[t];
    __syncthreads();
    if (t == 0) {
        int run = 0;
        for (int i = 0; i < NB; i++) { int c = s[i]; s[i] = run; run += c; }
        boff[NB] = run;   // == NE
    }
    __syncthreads();
    if (t < NB) { boff[t] = s[t]; bcur[t] = s[t]; }
}

// Each block claims a contiguous chunk per bucket, then writes packed records
// src | (dst_in_bucket << 17) into its exclusive chunk (dense, short window).
__global__ __launch_bounds__(256)
void bin_place_kernel(const int* __restrict__ esrc, const int* __restrict__ edst,
                      int* __restrict__ bcur, int* __restrict__ ebuf) {
    __shared__ int h[NB], base[NB], lcur[NB];
    int t = threadIdx.x;
    if (t < NB) h[t] = 0;
    __syncthreads();
    int e0 = blockIdx.x * EPB;
    for (int q = 0; q < EPB; q += 256) {
        int e = e0 + q + t;
        if (e < NE) atomicAdd(&h[edst[e] / NPB], 1);
    }
    __syncthreads();
    if (t < NB) {
        int c = h[t];
        base[t] = c ? atomicAdd(&bcur[t], c) : 0;
        lcur[t] = 0;
    }
    __syncthreads();
    for (int q = 0; q < EPB; q += 256) {
        int e = e0 + q + t;
        if (e < NE) {
            int d = edst[e], s = esrc[e];
            int b = d / NPB;
            int r = atomicAdd(&lcur[b], 1);
            ebuf[base[b] + r] = s | ((d - b * NPB) << 17);
        }
    }
}

// One block per bucket: per-node degree via LDS histogram.
__global__ __launch_bounds__(256)
void bucket_deg_kernel(const int* __restrict__ boff, const int* __restrict__ ebuf,
                       int* __restrict__ deg) {
    __shared__ int h[NPB];
    int b = blockIdx.x, t = threadIdx.x;
    for (int i = t; i < NPB; i += 256) h[i] = 0;
    __syncthreads();
    int jb = boff[b], je = boff[b + 1];
    for (int j = jb + t; j < je; j += 256) atomicAdd(&h[ebuf[j] >> 17], 1);
    __syncthreads();
    int n0 = b * NPB;
    for (int i = t; i < NPB; i += 256) {
        int n = n0 + i;
        if (n < NN) deg[n] = h[i] + 1;   // +1 self loop
    }
}

// One block per bucket: replay records with LDS cursors; sorted_src writes
// land in this block's exclusive CSR range (L2-local, written back once).
__global__ __launch_bounds__(256)
void bucket_scatter_kernel(const int* __restrict__ boff, const int* __restrict__ ebuf,
                           const int* __restrict__ off, int* __restrict__ sorted_src) {
    __shared__ int lcur[NPB];
    int b = blockIdx.x, t = threadIdx.x;
    int n0 = b * NPB;
    for (int i = t; i < NPB; i += 256) {
        int n = n0 + i;
        lcur[i] = (n < NN) ? off[n] + 1 : 0;   // +1: self loop occupies slot 0
    }
    __syncthreads();
    int jb = boff[b], je = boff[b + 1];
    for (int j = jb + t; j < je; j += 256) {
        int rec = ebuf[j];
        int p = atomicAdd(&lcur[rec >> 17], 1);
        sorted_src[p] = rec & 0x1FFFF;
    }
}

// ---------------- node-offset scan ----------------
__global__ __launch_bounds__(256)
void scan_block_kernel(const int* __restrict__ deg, int* __restrict__ off,
                       int* __restrict__ bsum) {
    __shared__ int s[256];
    int t = threadIdx.x, b = blockIdx.x, i = b * 256 + t;
    int v = (i < NN) ? deg[i] : 0;
    s[t] = v; __syncthreads();
#pragma unroll
    for (int o = 1; o < 256; o <<= 1) {
        int x = (t >= o) ? s[t - o] : 0;
        __syncthreads();
        s[t] += x;
        __syncthreads();
    }
    if (i < NN) off[i] = s[t] - v;
    if (t == 255) bsum[b] = s[255];
}

__global__ __launch_bounds__(256)
void scan_bsum_kernel(const int* __restrict__ bsum, int* __restrict__ bscan, int nb) {
    __shared__ int s[256];
    int t = threadIdx.x;
    int carry = 0;
    int nc = (nb + 255) / 256;
    for (int c = 0; c < nc; c++) {
        int i = c * 256 + t;
        int v = (i < nb) ? bsum[i] : 0;
        s[t] = v; __syncthreads();
#pragma unroll
        for (int o = 1; o < 256; o <<= 1) {
            int x = (t >= o) ? s[t - o] : 0;
            __syncthreads();
            s[t] += x;
            __syncthreads();
        }
        if (i < nb) bscan[i] = carry + s[t] - v;
        carry += s[255];
        __syncthreads();
    }
}

__global__ __launch_bounds__(256)
void place_kernel(int* __restrict__ off, const int* __restrict__ bscan,
                  int* __restrict__ sorted_src) {
    int i = blockIdx.x * 256 + threadIdx.x;
    if (i == 0) off[NN] = NT;
    if (i < NN) {
        int o = off[i] + bscan[i >> 8];
        off[i] = o;
        sorted_src[o] = i;   // self loop first
    }
}

// ---------------- fold weight blocks ----------------
__global__ __launch_bounds__(256)
void fold_B12_kernel(const float* __restrict__ W, const float* __restrict__ lw,
                     const float* __restrict__ as_, const float* __restrict__ ad_,
                     float* __restrict__ B, int F) {
    int t = blockIdx.x * 256 + threadIdx.x;
    if (t >= F * 88) return;
    int f = t / 88, j = t - f * 88;
    float v = 0.f;
    if (j < 40) v = W[f * 40 + j];
    else if (j < 80) v = lw[f * 40 + (j - 40)];
    else if (j < 84) {
        int h = j - 80; float s = 0.f;
        for (int d = 0; d < 10; d++) s += W[f * 40 + h * 10 + d] * as_[h * 10 + d];
        v = s;
    } else {
        int h = j - 84; float s = 0.f;
        for (int d = 0; d < 10; d++) s += W[f * 40 + h * 10 + d] * ad_[h * 10 + d];
        v = s;
    }
    B[t] = v;
}

__global__ __launch_bounds__(256)
void fold_B3_kernel(const float* __restrict__ W3, const float* __restrict__ as3,
                    const float* __restrict__ ad3, float* __restrict__ B) {
    int t = blockIdx.x * 256 + threadIdx.x;
    if (t >= 40 * 12) return;
    int f = t / 12, k = t - f * 12;
    float s = 0.f;
    if (k < 6) {
        int h = k;
        for (int c = 0; c < COUT; c++) s += W3[f * 726 + h * COUT + c] * as3[h * COUT + c];
    } else {
        int h = k - 6;
        for (int c = 0; c < COUT; c++) s += W3[f * 726 + h * COUT + c] * ad3[h * COUT + c];
    }
    B[t] = s;
}

// Fold W3/lw3 into bf16 MFMA B-fragment order.
__global__ __launch_bounds__(256)
void fold_Bf_kernel(const float* __restrict__ W3, const float* __restrict__ lw3,
                    __hip_bfloat16* __restrict__ Bf) {
    int t = blockIdx.x * 256 + threadIdx.x;
    if (t >= 9 * 8 * 64 * 8) return;
    int j = t & 7, lane = (t >> 3) & 63, ct = (t >> 9) & 7, kt = t >> 12;
    int k = kt * 32 + (lane >> 4) * 8 + j;
    int c = ct * 16 + (lane & 15);
    float v = 0.f;
    if (c < COUT) {
        if (k < 240) {
            int h = k / 40, f = k - h * 40;
            v = W3[f * 726 + h * COUT + c];
        } else if (k < 280) {
            int f = k - 240;
            v = lw3[f * COUT + c];
        }
    }
    Bf[t] = __float2bfloat16(v);
}

// ---------------- fused feature GEMM for layers 1/2 ----------------
template <int F>
__global__ __launch_bounds__(256)
void feature12_kernel(const float* __restrict__ A, const float* __restrict__ B,
                      const float* __restrict__ bias, const float* __restrict__ lbias,
                      float* __restrict__ xw, float* __restrict__ agg,
                      float* __restrict__ asrc, float* __restrict__ adst) {
    __shared__ float sB[F * 88];
    const int t = threadIdx.x;
    for (int i = t; i < F * 88; i += 256) sB[i] = B[i];

    const int lane = t & 63;
    const int p = __builtin_amdgcn_readfirstlane(t >> 6);
    const int r = blockIdx.x * 64 + lane;
    const bool valid = r < NN;
    const int rr = valid ? r : NN - 1;

    float a[F];
    if (F % 4 == 0) {
        const float4* A4 = reinterpret_cast<const float4*>(A + (size_t)rr * F);
#pragma unroll
        for (int q = 0; q < F / 4; q++) {
            float4 v = A4[q];
            a[4 * q] = v.x; a[4 * q + 1] = v.y; a[4 * q + 2] = v.z; a[4 * q + 3] = v.w;
        }
    } else {
        const float2* A2 = reinterpret_cast<const float2*>(A + (size_t)rr * F);
#pragma unroll
        for (int q = 0; q < F / 2; q++) {
            float2 v = A2[q];
            a[2 * q] = v.x; a[2 * q + 1] = v.y;
        }
        if (F & 1) a[F - 1] = A[(size_t)rr * F + F - 1];
    }
    __syncthreads();

    for (int g = p; g < 11; g += 4) {
        const int j0 = g * 8;
        float acc[8];
#pragma unroll
        for (int k = 0; k < 8; k++) acc[k] = 0.f;
#pragma unroll
        for (int f = 0; f < F; f++) {
            float av = a[f];
            float4 b0 = *reinterpret_cast<const float4*>(&sB[f * 88 + j0]);
            float4 b1 = *reinterpret_cast<const float4*>(&sB[f * 88 + j0 + 4]);
            acc[0] += av * b0.x; acc[1] += av * b0.y;
            acc[2] += av * b0.z; acc[3] += av * b0.w;
            acc[4] += av * b1.x; acc[5] += av * b1.y;
            acc[6] += av * b1.z; acc[7] += av * b1.w;
        }
        if (!valid) continue;
        if (j0 < 40) {
            *reinterpret_cast<float4*>(xw + (size_t)r * 40 + j0) =
                make_float4(acc[0], acc[1], acc[2], acc[3]);
            *reinterpret_cast<float4*>(xw + (size_t)r * 40 + j0 + 4) =
                make_float4(acc[4], acc[5], acc[6], acc[7]);
        } else if (j0 < 80) {
            int j = j0 - 40;
#pragma unroll
            for (int k = 0; k < 8; k++) acc[k] += bias[j + k] + lbias[j + k];
            *reinterpret_cast<float4*>(agg + (size_t)r * 40 + j) =
                make_float4(acc[0], acc[1], acc[2], acc[3]);
            *reinterpret_cast<float4*>(agg + (size_t)r * 40 + j + 4) =
                make_float4(acc[4], acc[5], acc[6], acc[7]);
        } else {
            *reinterpret_cast<float4*>(asrc + (size_t)r * 8) =
                make_float4(acc[0], acc[1], acc[2], acc[3]);
            *reinterpret_cast<float4*>(adst + (size_t)r * 8) =
                make_float4(acc[4], acc[5], acc[6], acc[7]);
        }
    }
}

// ---------------- layer 3 scores + bf16 h2 copies (zb + packed hp) ----------
__global__ __launch_bounds__(256)
void feature3_kernel(const float* __restrict__ A, const float* __restrict__ B,
                     float* __restrict__ asrc, float* __restrict__ adst,
                     __hip_bfloat16* __restrict__ zb, __hip_bfloat16* __restrict__ hp) {
    int r = blockIdx.x * 256 + threadIdx.x;
    if (r >= NN) return;
    float a[40];
    const float4* A4 = reinterpret_cast<const float4*>(A + (size_t)r * 40);
#pragma unroll
    for (int q = 0; q < 10; q++) {
        float4 v = A4[q];
        a[4 * q] = v.x; a[4 * q + 1] = v.y; a[4 * q + 2] = v.z; a[4 * q + 3] = v.w;
    }
    __hip_bfloat16* zr = zb + (size_t)r * 288 + 240;
    __hip_bfloat16* hr = hp + (size_t)r * 40;
#pragma unroll
    for (int f = 0; f < 40; f++) {
        __hip_bfloat16 v = __float2bfloat16(a[f]);
        zr[f] = v;
        hr[f] = v;
    }
#pragma unroll
    for (int f = 40; f < 48; f++) zr[f] = __float2bfloat16(0.f);

    float acc[12];
#pragma unroll
    for (int k = 0; k < 12; k++) acc[k] = 0.f;
#pragma unroll
    for (int f = 0; f < 40; f++) {
        float av = a[f];
#pragma unroll
        for (int k = 0; k < 12; k++) acc[k] += av * B[f * 12 + k];
    }
    *reinterpret_cast<float4*>(asrc + (size_t)r * 8) = make_float4(acc[0], acc[1], acc[2], acc[3]);
    *reinterpret_cast<float2*>(asrc + (size_t)r * 8 + 4) = make_float2(acc[4], acc[5]);
    *reinterpret_cast<float4*>(adst + (size_t)r * 8) = make_float4(acc[6], acc[7], acc[8], acc[9]);
    *reinterpret_cast<float2*>(adst + (size_t)r * 8 + 4) = make_float2(acc[10], acc[11]);
}

// ---------------- CSR aggregation, H=4, fused weights (LDS), fused ELU ------
// Wave per dst node. Chunks of 64 edges: phase A = lane k computes the 4
// exp(lrelu(.)) weights for edge c0+k (one exp per edge, no redundancy) into
// a per-wave LDS slice; phase B = FMA loop reads w/s via LDS broadcast.
// FMA order identical to the previous version -> same numerics.
__global__ __launch_bounds__(256)
void agg4_csr_kernel(const int* __restrict__ off, const int* __restrict__ srt,
                     const float* __restrict__ asrc, const float* __restrict__ adst,
                     const float* __restrict__ xw, float* agg) {
    __shared__ float sW[4][64 * 4];
    __shared__ int   sS[4][64];
    int t = threadIdx.x;
    int wslot = t >> 6;
    int wid = (blockIdx.x * 256 + t) >> 6;
    int d = __builtin_amdgcn_readfirstlane(wid);
    if (d >= NN) return;
    int lane = t & 63;
    bool act = lane < 40;
    int f = act ? lane : 0;
    int hh = f / 10;
    float4 bv = *reinterpret_cast<const float4*>(adst + (size_t)d * 8);
    int jb = off[d], je = off[d + 1];
    float acc = 0.f, ds = 0.f;
    for (int c0 = jb; c0 < je; c0 += 64) {
        int cnt = je - c0; if (cnt > 64) cnt = 64;
        if (lane < cnt) {   // phase A: one lane per edge
            int s = srt[c0 + lane];
            sS[wslot][lane] = s;
            float4 a = *reinterpret_cast<const float4*>(asrc + (size_t)s * 8);
            float4 w;
            w.x = __expf(lrelu(a.x + bv.x));
            w.y = __expf(lrelu(a.y + bv.y));
            w.z = __expf(lrelu(a.z + bv.z));
            w.w = __expf(lrelu(a.w + bv.w));
            *reinterpret_cast<float4*>(&sW[wslot][lane * 4]) = w;
        }
        int j = 0;          // phase B: FMA loop (same order as before)
        for (; j + 3 < cnt; j += 4) {
            int s0 = sS[wslot][j], s1 = sS[wslot][j + 1];
            int s2 = sS[wslot][j + 2], s3 = sS[wslot][j + 3];
            float w0 = sW[wslot][(j + 0) * 4 + hh];
            float w1 = sW[wslot][(j + 1) * 4 + hh];
            float w2 = sW[wslot][(j + 2) * 4 + hh];
            float w3 = sW[wslot][(j + 3) * 4 + hh];
            float x0 = xw[(size_t)s0 * 40 + f], x1 = xw[(size_t)s1 * 40 + f];
            float x2 = xw[(size_t)s2 * 40 + f], x3 = xw[(size_t)s3 * 40 + f];
            acc += w0 * x0; acc += w1 * x1; acc += w2 * x2; acc += w3 * x3;
            ds += (w0 + w1) + (w2 + w3);
        }
        for (; j < cnt; ++j) {
            int s = sS[wslot][j];
            float w = sW[wslot][j * 4 + hh];
            acc += w * xw[(size_t)s * 40 + f];
            ds += w;
        }
    }
    if (act) {
        float v = agg[(size_t)d * 40 + f] + acc / ds;
        agg[(size_t)d * 40 + f] = elu1(v);   // ELU fused (layers 1/2 only)
    }
}

// ---------------- CSR aggregation, H=6 -> bf16 z, fused weights (LDS) -------
__global__ __launch_bounds__(256)
void z6_csr_kernel(const int* __restrict__ off, const int* __restrict__ srt,
                   const float* __restrict__ asrc, const float* __restrict__ adst,
                   const __hip_bfloat16* __restrict__ hp, __hip_bfloat16* zb) {
    __shared__ float sW[4][64 * 6];
    __shared__ int   sS[4][64];
    int t = threadIdx.x;
    int wslot = t >> 6;
    int wid = (blockIdx.x * 256 + t) >> 6;
    int d = __builtin_amdgcn_readfirstlane(wid);
    if (d >= NN) return;
    int lane = t & 63;
    bool act = lane < 40;
    int f = act ? lane : 0;
    float4 bv0 = *reinterpret_cast<const float4*>(adst + (size_t)d * 8);
    float2 bv1 = *reinterpret_cast<const float2*>(adst + (size_t)d * 8 + 4);
    int jb = off[d], je = off[d + 1];
    float acc[6], ds[6];
#pragma unroll
    for (int h = 0; h < 6; h++) { acc[h] = 0.f; ds[h] = 0.f; }
    for (int c0 = jb; c0 < je; c0 += 64) {
        int cnt = je - c0; if (cnt > 64) cnt = 64;
        if (lane < cnt) {   // phase A
            int s = srt[c0 + lane];
            sS[wslot][lane] = s;
            float4 a0 = *reinterpret_cast<const float4*>(asrc + (size_t)s * 8);
            float2 a1 = *reinterpret_cast<const float2*>(asrc + (size_t)s * 8 + 4);
            float* wp = &sW[wslot][lane * 6];
            *reinterpret_cast<float4*>(wp) = make_float4(
                __expf(lrelu(a0.x + bv0.x)), __expf(lrelu(a0.y + bv0.y)),
                __expf(lrelu(a0.z + bv0.z)), __expf(lrelu(a0.w + bv0.w)));
            *reinterpret_cast<float2*>(wp + 4) = make_float2(
                __expf(lrelu(a1.x + bv1.x)), __expf(lrelu(a1.y + bv1.y)));
        }
        int j = 0;          // phase B (same pairing as before)
        for (; j + 1 < cnt; j += 2) {
            int s0 = sS[wslot][j], s1 = sS[wslot][j + 1];
            float hv0 = __bfloat162float(hp[(size_t)s0 * 40 + f]);
            float hv1 = __bfloat162float(hp[(size_t)s1 * 40 + f]);
            const float* wp = &sW[wslot][j * 6];
#pragma unroll
            for (int h = 0; h < 6; h++) {
                float w0 = wp[h], w1 = wp[6 + h];
                acc[h] += w0 * hv0; acc[h] += w1 * hv1;
                ds[h] += w0 + w1;
            }
        }
        for (; j < cnt; ++j) {
            int s = sS[wslot][j];
            float hv = __bfloat162float(hp[(size_t)s * 40 + f]);
            const float* wp = &sW[wslot][j * 6];
#pragma unroll
            for (int h = 0; h < 6; h++) {
                acc[h] += wp[h] * hv;
                ds[h] += wp[h];
            }
        }
    }
    if (act) {
#pragma unroll
        for (int h = 0; h < 6; h++)
            zb[(size_t)d * 288 + h * 40 + f] =
                __float2bfloat16(acc[h] / ds[h] * (1.0f / 6.0f));
    }
}

// ---------------- MFMA GEMM: out[100000x121] = A[100000x288]@B[288x128] + bias
__global__ __launch_bounds__(256)
void zgemm_mfma_kernel(const __hip_bfloat16* __restrict__ Ab,
                       const __hip_bfloat16* __restrict__ Bf,
                       const float* __restrict__ b3, const float* __restrict__ lb3,
                       float* __restrict__ out) {
    const int t = threadIdx.x;
    const int lane = t & 63, w = t >> 6;
    const int wr = w & 1, wc = w >> 1;
    const int n0 = blockIdx.x * 128;
    const short* As = (const short*)Ab;
    const short* Bs = (const short*)Bf;

    f32x4 acc[4][4];
#pragma unroll
    for (int i = 0; i < 4; i++)
#pragma unroll
        for (int j = 0; j < 4; j++) acc[i][j] = (f32x4){0.f, 0.f, 0.f, 0.f};

    const int arow = n0 + wr * 64 + (lane & 15);
    const int koff = (lane >> 4) * 8;

    for (int kk = 0; kk < 9; kk++) {
        bf16x8 af[4], bfr[4];
#pragma unroll
        for (int i = 0; i < 4; i++) {
            int r = arow + i * 16; if (r > NN - 1) r = NN - 1;
            af[i] = *(const bf16x8*)(As + (size_t)r * 288 + kk * 32 + koff);
        }
#pragma unroll
        for (int j = 0; j < 4; j++) {
            int ct = wc * 4 + j;
            bfr[j] = *(const bf16x8*)(Bs + (((size_t)kk * 8 + ct) * 64 + lane) * 8);
        }
#pragma unroll
        for (int i = 0; i < 4; i++)
#pragma unroll
            for (int j = 0; j < 4; j++)
                acc[i][j] = __builtin_amdgcn_mfma_f32_16x16x32_bf16(af[i], bfr[j], acc[i][j], 0, 0, 0);
    }

    const int c_base = wc * 64 + (lane & 15);
    const int r_quad = (lane >> 4) * 4;
#pragma unroll
    for (int j = 0; j < 4; j++) {
        int c = c_base + j * 16;
        if (c >= COUT) continue;
        float bias = b3[c] + lb3[c];
#pragma unroll
        for (int i = 0; i < 4; i++) {
            int nb = n0 + wr * 64 + i * 16 + r_quad;
#pragma unroll
            for (int q = 0; q < 4; q++) {
                int n = nb + q;
                if (n < NN) out[(size_t)n * COUT + c] = acc[i][j][q] + bias;
            }
        }
    }
}

extern "C" void kernel_launch(void* const* d_in, const int* in_sizes, int n_in,
                              void* d_out, int out_size, void* d_ws, size_t ws_size,
                              hipStream_t stream) {
    const float* x   = (const float*)d_in[0];
    const int*   ei  = (const int*)d_in[1];
    const float* W1  = (const float*)d_in[2];
    const float* as1 = (const float*)d_in[3];
    const float* ad1 = (const float*)d_in[4];
    const float* b1  = (const float*)d_in[5];
    const float* lw1 = (const float*)d_in[6];
    const float* lb1 = (const float*)d_in[7];
    const float* W2  = (const float*)d_in[8];
    const float* as2 = (const float*)d_in[9];
    const float* ad2 = (const float*)d_in[10];
    const float* b2  = (const float*)d_in[11];
    const float* lw2 = (const float*)d_in[12];
    const float* lb2 = (const float*)d_in[13];
    const float* W3  = (const float*)d_in[14];
    const float* as3 = (const float*)d_in[15];
    const float* ad3 = (const float*)d_in[16];
    const float* b3  = (const float*)d_in[17];
    const float* lw3 = (const float*)d_in[18];
    const float* lb3 = (const float*)d_in[19];
    float* out = (float*)d_out;
    float* ws  = (float*)d_ws;

    const int* esrc = ei;
    const int* edst = ei + NE;

    // ---- workspace layout (floats unless noted) ----
    float* xw   = ws;
    float* agg  = ws + 4000000;
    float* asrc = ws + 8000000;
    float* adst = ws + 8800000;
    float* Bc   = ws + 9600000;
    __hip_bfloat16* Bf = (__hip_bfloat16*)(ws + 9608000);
    __hip_bfloat16* zb = (__hip_bfloat16*)(ws + 9628000);
    __hip_bfloat16* hp = (__hip_bfloat16*)ws; // aliases xw (layer 3 only)
    int* ib     = (int*)(ws + 24028000);
    int* deg    = ib;                 // 100,352
    int* off    = ib + 100352;        // 100,001 (+pad)
    int* bcnt   = ib + 200704;        // 128
    int* boff   = ib + 200832;        // 129
    int* bcur   = ib + 200992;        // 128
    int* bsum   = ib + 300704;        // 512
    int* bscan  = ib + 301216;        // 512
    int* sorted = ib + 301728;        // 1,700,000 -> ends 2,001,728
    int* ebuf   = ib + 2001728;       // 1,600,000 -> ends 3,601,728

    const int nodeBlocks = (NN + 255) / 256;       // 391
    const int binBlocks  = (NE + EPB - 1) / EPB;   // 196
    const int waveBlocks = NN / 4;                 // 25000
    const int featBlocks = (NN + 63) / 64;         // 1563 (64 rows/block)

    // ---- bucketed CSR build ----
    zero_bcnt_kernel<<<1, 256, 0, stream>>>(bcnt);
    bin_count_kernel<<<binBlocks, 256, 0, stream>>>(edst, bcnt);
    bin_scan_kernel<<<1, 256, 0, stream>>>(bcnt, boff, bcur);
    bin_place_kernel<<<binBlocks, 256, 0, stream>>>(esrc, edst, bcur, ebuf);
    bucket_deg_kernel<<<NB, 256, 0, stream>>>(boff, ebuf, deg);
    scan_block_kernel<<<nodeBlocks, 256, 0, stream>>>(deg, off, bsum);
    scan_bsum_kernel<<<1, 256, 0, stream>>>(bsum, bscan, nodeBlocks);
    place_kernel<<<nodeBlocks, 256, 0, stream>>>(off, bscan, sorted);
    bucket_scatter_kernel<<<NB, 256, 0, stream>>>(boff, ebuf, off, sorted);

    // ---- layer 1 ----
    fold_B12_kernel<<<(FIN * 88 + 255) / 256, 256, 0, stream>>>(W1, lw1, as1, ad1, Bc, FIN);
    feature12_kernel<FIN><<<featBlocks, 256, 0, stream>>>(x, Bc, b1, lb1, xw, agg, asrc, adst);
    agg4_csr_kernel<<<waveBlocks, 256, 0, stream>>>(off, sorted, asrc, adst, xw, agg);

    // ---- layer 2 ----
    fold_B12_kernel<<<(HID * 88 + 255) / 256, 256, 0, stream>>>(W2, lw2, as2, ad2, Bc, HID);
    feature12_kernel<HID><<<featBlocks, 256, 0, stream>>>(agg, Bc, b2, lb2, xw, agg, asrc, adst);
    agg4_csr_kernel<<<waveBlocks, 256, 0, stream>>>(off, sorted, asrc, adst, xw, agg);

    // ---- layer 3 ----
    fold_B3_kernel<<<(40 * 12 + 255) / 256, 256, 0, stream>>>(W3, as3, ad3, Bc);
    fold_Bf_kernel<<<(9 * 8 * 64 * 8 + 255) / 256, 256, 0, stream>>>(W3, lw3, Bf);
    feature3_kernel<<<nodeBlocks, 256, 0, stream>>>(agg, Bc, asrc, adst, zb, hp);
    z6_csr_kernel<<<waveBlocks, 256, 0, stream>>>(off, sorted, asrc, adst, hp, zb);
    zgemm_mfma_kernel<<<(NN + 127) / 128, 256, 0, stream>>>(zb, Bf, b3, lb3, out);
}

// Round 6
// 545.931 us; speedup vs baseline: 1.5038x; 1.0018x over previous
//
#include <hip/hip_runtime.h>
#include <hip/hip_bf16.h>
#include <math.h>

// GAT x3 on N=100000 nodes, E=1600000 edges (+ self loops).
// Round 11: z6 phase-B diet. Counters showed z6 @83us, VALUBusy 64%: the
// per-edge cost was 6 scalar ds_read_b32 (24B weight row, unvectorizable)
// + 6 redundant denominator adds in all 64 lanes. Changes:
//  - sW padded to [64][8]: weight row read = ds_read_b128 + ds_read_b64.
//  - denominator via per-lane phase-A partials + one shfl_xor tree reduce
//    per node (removes 6 adds/edge/lane; fp32-noise-level order change).
//  - 4-edge unroll with gathers issued up front; s*40 precomputed in LDS
//    (also in agg4).
// (R10: fused weights in LDS; R9: feature12 LDS-B; R8: bucketed CSR.)

#define NN 100000
#define NE 1600000
#define NT (NE + NN)
#define FIN 50
#define HID 40
#define COUT 121

#define NB 128           // buckets
#define NPB 782          // nodes per bucket (128*782 = 100096 >= NN)
#define EPB 8192         // edges per bin block

typedef __attribute__((ext_vector_type(8))) short bf16x8;
typedef __attribute__((ext_vector_type(4))) float f32x4;

__device__ __forceinline__ float lrelu(float x) { return fmaxf(x, 0.2f * x); }
__device__ __forceinline__ float elu1(float x)  { return x > 0.f ? x : __expf(x) - 1.f; }

// ---------------- bucketed CSR build ----------------
__global__ __launch_bounds__(256)
void zero_bcnt_kernel(int* __restrict__ bcnt) {
    int t = threadIdx.x;
    if (t < NB) bcnt[t] = 0;
}

__global__ __launch_bounds__(256)
void bin_count_kernel(const int* __restrict__ edst, int* __restrict__ bcnt) {
    __shared__ int h[NB];
    int t = threadIdx.x;
    if (t < NB) h[t] = 0;
    __syncthreads();
    int e0 = blockIdx.x * EPB;
    for (int q = 0; q < EPB; q += 256) {
        int e = e0 + q + t;
        if (e < NE) atomicAdd(&h[edst[e] / NPB], 1);
    }
    __syncthreads();
    if (t < NB && h[t]) atomicAdd(&bcnt[t], h[t]);
}

__global__ __launch_bounds__(256)
void bin_scan_kernel(const int* __restrict__ bcnt, int* __restrict__ boff,
                     int* __restrict__ bcur) {
    __shared__ int s[NB];
    int t = threadIdx.x;
    if (t < NB) s[t] = bcnt[t];
    __syncthreads();
    if (t == 0) {
        int run = 0;
        for (int i = 0; i < NB; i++) { int c = s[i]; s[i] = run; run += c; }
        boff[NB] = run;   // == NE
    }
    __syncthreads();
    if (t < NB) { boff[t] = s[t]; bcur[t] = s[t]; }
}

// Each block claims a contiguous chunk per bucket, then writes packed records
// src | (dst_in_bucket << 17) into its exclusive chunk (dense, short window).
__global__ __launch_bounds__(256)
void bin_place_kernel(const int* __restrict__ esrc, const int* __restrict__ edst,
                      int* __restrict__ bcur, int* __restrict__ ebuf) {
    __shared__ int h[NB], base[NB], lcur[NB];
    int t = threadIdx.x;
    if (t < NB) h[t] = 0;
    __syncthreads();
    int e0 = blockIdx.x * EPB;
    for (int q = 0; q < EPB; q += 256) {
        int e = e0 + q + t;
        if (e < NE) atomicAdd(&h[edst[e] / NPB], 1);
    }
    __syncthreads();
    if (t < NB) {
        int c = h[t];
        base[t] = c ? atomicAdd(&bcur[t], c) : 0;
        lcur[t] = 0;
    }
    __syncthreads();
    for (int q = 0; q < EPB; q += 256) {
        int e = e0 + q + t;
        if (e < NE) {
            int d = edst[e], s = esrc[e];
            int b = d / NPB;
            int r = atomicAdd(&lcur[b], 1);
            ebuf[base[b] + r] = s | ((d - b * NPB) << 17);
        }
    }
}

// One block per bucket: per-node degree via LDS histogram.
__global__ __launch_bounds__(256)
void bucket_deg_kernel(const int* __restrict__ boff, const int* __restrict__ ebuf,
                       int* __restrict__ deg) {
    __shared__ int h[NPB];
    int b = blockIdx.x, t = threadIdx.x;
    for (int i = t; i < NPB; i += 256) h[i] = 0;
    __syncthreads();
    int jb = boff[b], je = boff[b + 1];
    for (int j = jb + t; j < je; j += 256) atomicAdd(&h[ebuf[j] >> 17], 1);
    __syncthreads();
    int n0 = b * NPB;
    for (int i = t; i < NPB; i += 256) {
        int n = n0 + i;
        if (n < NN) deg[n] = h[i] + 1;   // +1 self loop
    }
}

// One block per bucket: replay records with LDS cursors; sorted_src writes
// land in this block's exclusive CSR range (L2-local, written back once).
__global__ __launch_bounds__(256)
void bucket_scatter_kernel(const int* __restrict__ boff, const int* __restrict__ ebuf,
                           const int* __restrict__ off, int* __restrict__ sorted_src) {
    __shared__ int lcur[NPB];
    int b = blockIdx.x, t = threadIdx.x;
    int n0 = b * NPB;
    for (int i = t; i < NPB; i += 256) {
        int n = n0 + i;
        lcur[i] = (n < NN) ? off[n] + 1 : 0;   // +1: self loop occupies slot 0
    }
    __syncthreads();
    int jb = boff[b], je = boff[b + 1];
    for (int j = jb + t; j < je; j += 256) {
        int rec = ebuf[j];
        int p = atomicAdd(&lcur[rec >> 17], 1);
        sorted_src[p] = rec & 0x1FFFF;
    }
}

// ---------------- node-offset scan ----------------
__global__ __launch_bounds__(256)
void scan_block_kernel(const int* __restrict__ deg, int* __restrict__ off,
                       int* __restrict__ bsum) {
    __shared__ int s[256];
    int t = threadIdx.x, b = blockIdx.x, i = b * 256 + t;
    int v = (i < NN) ? deg[i] : 0;
    s[t] = v; __syncthreads();
#pragma unroll
    for (int o = 1; o < 256; o <<= 1) {
        int x = (t >= o) ? s[t - o] : 0;
        __syncthreads();
        s[t] += x;
        __syncthreads();
    }
    if (i < NN) off[i] = s[t] - v;
    if (t == 255) bsum[b] = s[255];
}

__global__ __launch_bounds__(256)
void scan_bsum_kernel(const int* __restrict__ bsum, int* __restrict__ bscan, int nb) {
    __shared__ int s[256];
    int t = threadIdx.x;
    int carry = 0;
    int nc = (nb + 255) / 256;
    for (int c = 0; c < nc; c++) {
        int i = c * 256 + t;
        int v = (i < nb) ? bsum[i] : 0;
        s[t] = v; __syncthreads();
#pragma unroll
        for (int o = 1; o < 256; o <<= 1) {
            int x = (t >= o) ? s[t - o] : 0;
            __syncthreads();
            s[t] += x;
            __syncthreads();
        }
        if (i < nb) bscan[i] = carry + s[t] - v;
        carry += s[255];
        __syncthreads();
    }
}

__global__ __launch_bounds__(256)
void place_kernel(int* __restrict__ off, const int* __restrict__ bscan,
                  int* __restrict__ sorted_src) {
    int i = blockIdx.x * 256 + threadIdx.x;
    if (i == 0) off[NN] = NT;
    if (i < NN) {
        int o = off[i] + bscan[i >> 8];
        off[i] = o;
        sorted_src[o] = i;   // self loop first
    }
}

// ---------------- fold weight blocks ----------------
__global__ __launch_bounds__(256)
void fold_B12_kernel(const float* __restrict__ W, const float* __restrict__ lw,
                     const float* __restrict__ as_, const float* __restrict__ ad_,
                     float* __restrict__ B, int F) {
    int t = blockIdx.x * 256 + threadIdx.x;
    if (t >= F * 88) return;
    int f = t / 88, j = t - f * 88;
    float v = 0.f;
    if (j < 40) v = W[f * 40 + j];
    else if (j < 80) v = lw[f * 40 + (j - 40)];
    else if (j < 84) {
        int h = j - 80; float s = 0.f;
        for (int d = 0; d < 10; d++) s += W[f * 40 + h * 10 + d] * as_[h * 10 + d];
        v = s;
    } else {
        int h = j - 84; float s = 0.f;
        for (int d = 0; d < 10; d++) s += W[f * 40 + h * 10 + d] * ad_[h * 10 + d];
        v = s;
    }
    B[t] = v;
}

__global__ __launch_bounds__(256)
void fold_B3_kernel(const float* __restrict__ W3, const float* __restrict__ as3,
                    const float* __restrict__ ad3, float* __restrict__ B) {
    int t = blockIdx.x * 256 + threadIdx.x;
    if (t >= 40 * 12) return;
    int f = t / 12, k = t - f * 12;
    float s = 0.f;
    if (k < 6) {
        int h = k;
        for (int c = 0; c < COUT; c++) s += W3[f * 726 + h * COUT + c] * as3[h * COUT + c];
    } else {
        int h = k - 6;
        for (int c = 0; c < COUT; c++) s += W3[f * 726 + h * COUT + c] * ad3[h * COUT + c];
    }
    B[t] = s;
}

// Fold W3/lw3 into bf16 MFMA B-fragment order.
__global__ __launch_bounds__(256)
void fold_Bf_kernel(const float* __restrict__ W3, const float* __restrict__ lw3,
                    __hip_bfloat16* __restrict__ Bf) {
    int t = blockIdx.x * 256 + threadIdx.x;
    if (t >= 9 * 8 * 64 * 8) return;
    int j = t & 7, lane = (t >> 3) & 63, ct = (t >> 9) & 7, kt = t >> 12;
    int k = kt * 32 + (lane >> 4) * 8 + j;
    int c = ct * 16 + (lane & 15);
    float v = 0.f;
    if (c < COUT) {
        if (k < 240) {
            int h = k / 40, f = k - h * 40;
            v = W3[f * 726 + h * COUT + c];
        } else if (k < 280) {
            int f = k - 240;
            v = lw3[f * COUT + c];
        }
    }
    Bf[t] = __float2bfloat16(v);
}

// ---------------- fused feature GEMM for layers 1/2 ----------------
template <int F>
__global__ __launch_bounds__(256)
void feature12_kernel(const float* __restrict__ A, const float* __restrict__ B,
                      const float* __restrict__ bias, const float* __restrict__ lbias,
                      float* __restrict__ xw, float* __restrict__ agg,
                      float* __restrict__ asrc, float* __restrict__ adst) {
    __shared__ float sB[F * 88];
    const int t = threadIdx.x;
    for (int i = t; i < F * 88; i += 256) sB[i] = B[i];

    const int lane = t & 63;
    const int p = __builtin_amdgcn_readfirstlane(t >> 6);
    const int r = blockIdx.x * 64 + lane;
    const bool valid = r < NN;
    const int rr = valid ? r : NN - 1;

    float a[F];
    if (F % 4 == 0) {
        const float4* A4 = reinterpret_cast<const float4*>(A + (size_t)rr * F);
#pragma unroll
        for (int q = 0; q < F / 4; q++) {
            float4 v = A4[q];
            a[4 * q] = v.x; a[4 * q + 1] = v.y; a[4 * q + 2] = v.z; a[4 * q + 3] = v.w;
        }
    } else {
        const float2* A2 = reinterpret_cast<const float2*>(A + (size_t)rr * F);
#pragma unroll
        for (int q = 0; q < F / 2; q++) {
            float2 v = A2[q];
            a[2 * q] = v.x; a[2 * q + 1] = v.y;
        }
        if (F & 1) a[F - 1] = A[(size_t)rr * F + F - 1];
    }
    __syncthreads();

    for (int g = p; g < 11; g += 4) {
        const int j0 = g * 8;
        float acc[8];
#pragma unroll
        for (int k = 0; k < 8; k++) acc[k] = 0.f;
#pragma unroll
        for (int f = 0; f < F; f++) {
            float av = a[f];
            float4 b0 = *reinterpret_cast<const float4*>(&sB[f * 88 + j0]);
            float4 b1 = *reinterpret_cast<const float4*>(&sB[f * 88 + j0 + 4]);
            acc[0] += av * b0.x; acc[1] += av * b0.y;
            acc[2] += av * b0.z; acc[3] += av * b0.w;
            acc[4] += av * b1.x; acc[5] += av * b1.y;
            acc[6] += av * b1.z; acc[7] += av * b1.w;
        }
        if (!valid) continue;
        if (j0 < 40) {
            *reinterpret_cast<float4*>(xw + (size_t)r * 40 + j0) =
                make_float4(acc[0], acc[1], acc[2], acc[3]);
            *reinterpret_cast<float4*>(xw + (size_t)r * 40 + j0 + 4) =
                make_float4(acc[4], acc[5], acc[6], acc[7]);
        } else if (j0 < 80) {
            int j = j0 - 40;
#pragma unroll
            for (int k = 0; k < 8; k++) acc[k] += bias[j + k] + lbias[j + k];
            *reinterpret_cast<float4*>(agg + (size_t)r * 40 + j) =
                make_float4(acc[0], acc[1], acc[2], acc[3]);
            *reinterpret_cast<float4*>(agg + (size_t)r * 40 + j + 4) =
                make_float4(acc[4], acc[5], acc[6], acc[7]);
        } else {
            *reinterpret_cast<float4*>(asrc + (size_t)r * 8) =
                make_float4(acc[0], acc[1], acc[2], acc[3]);
            *reinterpret_cast<float4*>(adst + (size_t)r * 8) =
                make_float4(acc[4], acc[5], acc[6], acc[7]);
        }
    }
}

// ---------------- layer 3 scores + bf16 h2 copies (zb + packed hp) ----------
__global__ __launch_bounds__(256)
void feature3_kernel(const float* __restrict__ A, const float* __restrict__ B,
                     float* __restrict__ asrc, float* __restrict__ adst,
                     __hip_bfloat16* __restrict__ zb, __hip_bfloat16* __restrict__ hp) {
    int r = blockIdx.x * 256 + threadIdx.x;
    if (r >= NN) return;
    float a[40];
    const float4* A4 = reinterpret_cast<const float4*>(A + (size_t)r * 40);
#pragma unroll
    for (int q = 0; q < 10; q++) {
        float4 v = A4[q];
        a[4 * q] = v.x; a[4 * q + 1] = v.y; a[4 * q + 2] = v.z; a[4 * q + 3] = v.w;
    }
    __hip_bfloat16* zr = zb + (size_t)r * 288 + 240;
    __hip_bfloat16* hr = hp + (size_t)r * 40;
#pragma unroll
    for (int f = 0; f < 40; f++) {
        __hip_bfloat16 v = __float2bfloat16(a[f]);
        zr[f] = v;
        hr[f] = v;
    }
#pragma unroll
    for (int f = 40; f < 48; f++) zr[f] = __float2bfloat16(0.f);

    float acc[12];
#pragma unroll
    for (int k = 0; k < 12; k++) acc[k] = 0.f;
#pragma unroll
    for (int f = 0; f < 40; f++) {
        float av = a[f];
#pragma unroll
        for (int k = 0; k < 12; k++) acc[k] += av * B[f * 12 + k];
    }
    *reinterpret_cast<float4*>(asrc + (size_t)r * 8) = make_float4(acc[0], acc[1], acc[2], acc[3]);
    *reinterpret_cast<float2*>(asrc + (size_t)r * 8 + 4) = make_float2(acc[4], acc[5]);
    *reinterpret_cast<float4*>(adst + (size_t)r * 8) = make_float4(acc[6], acc[7], acc[8], acc[9]);
    *reinterpret_cast<float2*>(adst + (size_t)r * 8 + 4) = make_float2(acc[10], acc[11]);
}

// ---------------- CSR aggregation, H=4, fused weights (LDS), fused ELU ------
// Wave per dst node. Chunks of 64 edges: phase A = lane k computes the 4
// exp(lrelu(.)) weights for edge c0+k into a per-wave LDS slice (stores
// s*40 so phase B skips the row-offset mul); phase B = FMA loop reads w/s
// via wave-uniform LDS broadcast. FMA order unchanged -> same numerics.
__global__ __launch_bounds__(256)
void agg4_csr_kernel(const int* __restrict__ off, const int* __restrict__ srt,
                     const float* __restrict__ asrc, const float* __restrict__ adst,
                     const float* __restrict__ xw, float* agg) {
    __shared__ float sW[4][64 * 4];
    __shared__ int   sS[4][64];
    int t = threadIdx.x;
    int wslot = t >> 6;
    int wid = (blockIdx.x * 256 + t) >> 6;
    int d = __builtin_amdgcn_readfirstlane(wid);
    if (d >= NN) return;
    int lane = t & 63;
    bool act = lane < 40;
    int f = act ? lane : 0;
    int hh = f / 10;
    float4 bv = *reinterpret_cast<const float4*>(adst + (size_t)d * 8);
    int jb = off[d], je = off[d + 1];
    float acc = 0.f, ds = 0.f;
    for (int c0 = jb; c0 < je; c0 += 64) {
        int cnt = je - c0; if (cnt > 64) cnt = 64;
        if (lane < cnt) {   // phase A: one lane per edge
            int s = srt[c0 + lane];
            sS[wslot][lane] = s * 40;
            float4 a = *reinterpret_cast<const float4*>(asrc + (size_t)s * 8);
            float4 w;
            w.x = __expf(lrelu(a.x + bv.x));
            w.y = __expf(lrelu(a.y + bv.y));
            w.z = __expf(lrelu(a.z + bv.z));
            w.w = __expf(lrelu(a.w + bv.w));
            *reinterpret_cast<float4*>(&sW[wslot][lane * 4]) = w;
        }
        int j = 0;          // phase B: FMA loop (same order as before)
        for (; j + 3 < cnt; j += 4) {
            int o0 = sS[wslot][j], o1 = sS[wslot][j + 1];
            int o2 = sS[wslot][j + 2], o3 = sS[wslot][j + 3];
            float w0 = sW[wslot][(j + 0) * 4 + hh];
            float w1 = sW[wslot][(j + 1) * 4 + hh];
            float w2 = sW[wslot][(j + 2) * 4 + hh];
            float w3 = sW[wslot][(j + 3) * 4 + hh];
            float x0 = xw[o0 + f], x1 = xw[o1 + f];
            float x2 = xw[o2 + f], x3 = xw[o3 + f];
            acc += w0 * x0; acc += w1 * x1; acc += w2 * x2; acc += w3 * x3;
            ds += (w0 + w1) + (w2 + w3);
        }
        for (; j < cnt; ++j) {
            int o = sS[wslot][j];
            float w = sW[wslot][j * 4 + hh];
            acc += w * xw[o + f];
            ds += w;
        }
    }
    if (act) {
        float v = agg[(size_t)d * 40 + f] + acc / ds;
        agg[(size_t)d * 40 + f] = elu1(v);   // ELU fused (layers 1/2 only)
    }
}

// ---------------- CSR aggregation, H=6 -> bf16 z, fused weights (LDS) -------
// sW padded to [64][8]: phase-B weight row = ds_read_b128 + ds_read_b64.
// Denominator via per-lane phase-A partials + shfl_xor tree reduce per node.
// 4-edge unroll, gathers issued up front.
__global__ __launch_bounds__(256)
void z6_csr_kernel(const int* __restrict__ off, const int* __restrict__ srt,
                   const float* __restrict__ asrc, const float* __restrict__ adst,
                   const __hip_bfloat16* __restrict__ hp, __hip_bfloat16* zb) {
    __shared__ float sW[4][64 * 8];
    __shared__ int   sS[4][64];
    int t = threadIdx.x;
    int wslot = t >> 6;
    int wid = (blockIdx.x * 256 + t) >> 6;
    int d = __builtin_amdgcn_readfirstlane(wid);
    if (d >= NN) return;
    int lane = t & 63;
    bool act = lane < 40;
    int f = act ? lane : 0;
    float4 bv0 = *reinterpret_cast<const float4*>(adst + (size_t)d * 8);
    float2 bv1 = *reinterpret_cast<const float2*>(adst + (size_t)d * 8 + 4);
    int jb = off[d], je = off[d + 1];
    float acc[6], dsp[6];
#pragma unroll
    for (int h = 0; h < 6; h++) { acc[h] = 0.f; dsp[h] = 0.f; }
    for (int c0 = jb; c0 < je; c0 += 64) {
        int cnt = je - c0; if (cnt > 64) cnt = 64;
        if (lane < cnt) {   // phase A: one lane per edge; private ds partials
            int s = srt[c0 + lane];
            sS[wslot][lane] = s * 40;
            float4 a0 = *reinterpret_cast<const float4*>(asrc + (size_t)s * 8);
            float2 a1 = *reinterpret_cast<const float2*>(asrc + (size_t)s * 8 + 4);
            float w0 = __expf(lrelu(a0.x + bv0.x));
            float w1 = __expf(lrelu(a0.y + bv0.y));
            float w2 = __expf(lrelu(a0.z + bv0.z));
            float w3 = __expf(lrelu(a0.w + bv0.w));
            float w4 = __expf(lrelu(a1.x + bv1.x));
            float w5 = __expf(lrelu(a1.y + bv1.y));
            float* wp = &sW[wslot][lane * 8];
            *reinterpret_cast<float4*>(wp)     = make_float4(w0, w1, w2, w3);
            *reinterpret_cast<float2*>(wp + 4) = make_float2(w4, w5);
            dsp[0] += w0; dsp[1] += w1; dsp[2] += w2;
            dsp[3] += w3; dsp[4] += w4; dsp[5] += w5;
        }
        int j = 0;          // phase B: acc order = edge order (unchanged)
        for (; j + 3 < cnt; j += 4) {
            int o0 = sS[wslot][j],     o1 = sS[wslot][j + 1];
            int o2 = sS[wslot][j + 2], o3 = sS[wslot][j + 3];
            float hv0 = __bfloat162float(hp[o0 + f]);
            float hv1 = __bfloat162float(hp[o1 + f]);
            float hv2 = __bfloat162float(hp[o2 + f]);
            float hv3 = __bfloat162float(hp[o3 + f]);
            const float4 wa0 = *reinterpret_cast<const float4*>(&sW[wslot][(j + 0) * 8]);
            const float2 wb0 = *reinterpret_cast<const float2*>(&sW[wslot][(j + 0) * 8 + 4]);
            const float4 wa1 = *reinterpret_cast<const float4*>(&sW[wslot][(j + 1) * 8]);
            const float2 wb1 = *reinterpret_cast<const float2*>(&sW[wslot][(j + 1) * 8 + 4]);
            const float4 wa2 = *reinterpret_cast<const float4*>(&sW[wslot][(j + 2) * 8]);
            const float2 wb2 = *reinterpret_cast<const float2*>(&sW[wslot][(j + 2) * 8 + 4]);
            const float4 wa3 = *reinterpret_cast<const float4*>(&sW[wslot][(j + 3) * 8]);
            const float2 wb3 = *reinterpret_cast<const float2*>(&sW[wslot][(j + 3) * 8 + 4]);
            acc[0] += wa0.x * hv0; acc[1] += wa0.y * hv0; acc[2] += wa0.z * hv0;
            acc[3] += wa0.w * hv0; acc[4] += wb0.x * hv0; acc[5] += wb0.y * hv0;
            acc[0] += wa1.x * hv1; acc[1] += wa1.y * hv1; acc[2] += wa1.z * hv1;
            acc[3] += wa1.w * hv1; acc[4] += wb1.x * hv1; acc[5] += wb1.y * hv1;
            acc[0] += wa2.x * hv2; acc[1] += wa2.y * hv2; acc[2] += wa2.z * hv2;
            acc[3] += wa2.w * hv2; acc[4] += wb2.x * hv2; acc[5] += wb2.y * hv2;
            acc[0] += wa3.x * hv3; acc[1] += wa3.y * hv3; acc[2] += wa3.z * hv3;
            acc[3] += wa3.w * hv3; acc[4] += wb3.x * hv3; acc[5] += wb3.y * hv3;
        }
        for (; j < cnt; ++j) {
            int o = sS[wslot][j];
            float hv = __bfloat162float(hp[o + f]);
            const float4 wa = *reinterpret_cast<const float4*>(&sW[wslot][j * 8]);
            const float2 wb = *reinterpret_cast<const float2*>(&sW[wslot][j * 8 + 4]);
            acc[0] += wa.x * hv; acc[1] += wa.y * hv; acc[2] += wa.z * hv;
            acc[3] += wa.w * hv; acc[4] += wb.x * hv; acc[5] += wb.y * hv;
        }
    }
    // reduce per-lane denominator partials across the wave (tree order)
#pragma unroll
    for (int h = 0; h < 6; h++) {
        float v = dsp[h];
#pragma unroll
        for (int o = 1; o < 64; o <<= 1) v += __shfl_xor(v, o, 64);
        dsp[h] = v;
    }
    if (act) {
#pragma unroll
        for (int h = 0; h < 6; h++)
            zb[(size_t)d * 288 + h * 40 + f] =
                __float2bfloat16(acc[h] / dsp[h] * (1.0f / 6.0f));
    }
}

// ---------------- MFMA GEMM: out[100000x121] = A[100000x288]@B[288x128] + bias
__global__ __launch_bounds__(256)
void zgemm_mfma_kernel(const __hip_bfloat16* __restrict__ Ab,
                       const __hip_bfloat16* __restrict__ Bf,
                       const float* __restrict__ b3, const float* __restrict__ lb3,
                       float* __restrict__ out) {
    const int t = threadIdx.x;
    const int lane = t & 63, w = t >> 6;
    const int wr = w & 1, wc = w >> 1;
    const int n0 = blockIdx.x * 128;
    const short* As = (const short*)Ab;
    const short* Bs = (const short*)Bf;

    f32x4 acc[4][4];
#pragma unroll
    for (int i = 0; i < 4; i++)
#pragma unroll
        for (int j = 0; j < 4; j++) acc[i][j] = (f32x4){0.f, 0.f, 0.f, 0.f};

    const int arow = n0 + wr * 64 + (lane & 15);
    const int koff = (lane >> 4) * 8;

    for (int kk = 0; kk < 9; kk++) {
        bf16x8 af[4], bfr[4];
#pragma unroll
        for (int i = 0; i < 4; i++) {
            int r = arow + i * 16; if (r > NN - 1) r = NN - 1;
            af[i] = *(const bf16x8*)(As + (size_t)r * 288 + kk * 32 + koff);
        }
#pragma unroll
        for (int j = 0; j < 4; j++) {
            int ct = wc * 4 + j;
            bfr[j] = *(const bf16x8*)(Bs + (((size_t)kk * 8 + ct) * 64 + lane) * 8);
        }
#pragma unroll
        for (int i = 0; i < 4; i++)
#pragma unroll
            for (int j = 0; j < 4; j++)
                acc[i][j] = __builtin_amdgcn_mfma_f32_16x16x32_bf16(af[i], bfr[j], acc[i][j], 0, 0, 0);
    }

    const int c_base = wc * 64 + (lane & 15);
    const int r_quad = (lane >> 4) * 4;
#pragma unroll
    for (int j = 0; j < 4; j++) {
        int c = c_base + j * 16;
        if (c >= COUT) continue;
        float bias = b3[c] + lb3[c];
#pragma unroll
        for (int i = 0; i < 4; i++) {
            int nb = n0 + wr * 64 + i * 16 + r_quad;
#pragma unroll
            for (int q = 0; q < 4; q++) {
                int n = nb + q;
                if (n < NN) out[(size_t)n * COUT + c] = acc[i][j][q] + bias;
            }
        }
    }
}

extern "C" void kernel_launch(void* const* d_in, const int* in_sizes, int n_in,
                              void* d_out, int out_size, void* d_ws, size_t ws_size,
                              hipStream_t stream) {
    const float* x   = (const float*)d_in[0];
    const int*   ei  = (const int*)d_in[1];
    const float* W1  = (const float*)d_in[2];
    const float* as1 = (const float*)d_in[3];
    const float* ad1 = (const float*)d_in[4];
    const float* b1  = (const float*)d_in[5];
    const float* lw1 = (const float*)d_in[6];
    const float* lb1 = (const float*)d_in[7];
    const float* W2  = (const float*)d_in[8];
    const float* as2 = (const float*)d_in[9];
    const float* ad2 = (const float*)d_in[10];
    const float* b2  = (const float*)d_in[11];
    const float* lw2 = (const float*)d_in[12];
    const float* lb2 = (const float*)d_in[13];
    const float* W3  = (const float*)d_in[14];
    const float* as3 = (const float*)d_in[15];
    const float* ad3 = (const float*)d_in[16];
    const float* b3  = (const float*)d_in[17];
    const float* lw3 = (const float*)d_in[18];
    const float* lb3 = (const float*)d_in[19];
    float* out = (float*)d_out;
    float* ws  = (float*)d_ws;

    const int* esrc = ei;
    const int* edst = ei + NE;

    // ---- workspace layout (floats unless noted) ----
    float* xw   = ws;
    float* agg  = ws + 4000000;
    float* asrc = ws + 8000000;
    float* adst = ws + 8800000;
    float* Bc   = ws + 9600000;
    __hip_bfloat16* Bf = (__hip_bfloat16*)(ws + 9608000);
    __hip_bfloat16* zb = (__hip_bfloat16*)(ws + 9628000);
    __hip_bfloat16* hp = (__hip_bfloat16*)ws; // aliases xw (layer 3 only)
    int* ib     = (int*)(ws + 24028000);
    int* deg    = ib;                 // 100,352
    int* off    = ib + 100352;        // 100,001 (+pad)
    int* bcnt   = ib + 200704;        // 128
    int* boff   = ib + 200832;        // 129
    int* bcur   = ib + 200992;        // 128
    int* bsum   = ib + 300704;        // 512
    int* bscan  = ib + 301216;        // 512
    int* sorted = ib + 301728;        // 1,700,000 -> ends 2,001,728
    int* ebuf   = ib + 2001728;       // 1,600,000 -> ends 3,601,728

    const int nodeBlocks = (NN + 255) / 256;       // 391
    const int binBlocks  = (NE + EPB - 1) / EPB;   // 196
    const int waveBlocks = NN / 4;                 // 25000
    const int featBlocks = (NN + 63) / 64;         // 1563 (64 rows/block)

    // ---- bucketed CSR build ----
    zero_bcnt_kernel<<<1, 256, 0, stream>>>(bcnt);
    bin_count_kernel<<<binBlocks, 256, 0, stream>>>(edst, bcnt);
    bin_scan_kernel<<<1, 256, 0, stream>>>(bcnt, boff, bcur);
    bin_place_kernel<<<binBlocks, 256, 0, stream>>>(esrc, edst, bcur, ebuf);
    bucket_deg_kernel<<<NB, 256, 0, stream>>>(boff, ebuf, deg);
    scan_block_kernel<<<nodeBlocks, 256, 0, stream>>>(deg, off, bsum);
    scan_bsum_kernel<<<1, 256, 0, stream>>>(bsum, bscan, nodeBlocks);
    place_kernel<<<nodeBlocks, 256, 0, stream>>>(off, bscan, sorted);
    bucket_scatter_kernel<<<NB, 256, 0, stream>>>(boff, ebuf, off, sorted);

    // ---- layer 1 ----
    fold_B12_kernel<<<(FIN * 88 + 255) / 256, 256, 0, stream>>>(W1, lw1, as1, ad1, Bc, FIN);
    feature12_kernel<FIN><<<featBlocks, 256, 0, stream>>>(x, Bc, b1, lb1, xw, agg, asrc, adst);
    agg4_csr_kernel<<<waveBlocks, 256, 0, stream>>>(off, sorted, asrc, adst, xw, agg);

    // ---- layer 2 ----
    fold_B12_kernel<<<(HID * 88 + 255) / 256, 256, 0, stream>>>(W2, lw2, as2, ad2, Bc, HID);
    feature12_kernel<HID><<<featBlocks, 256, 0, stream>>>(agg, Bc, b2, lb2, xw, agg, asrc, adst);
    agg4_csr_kernel<<<waveBlocks, 256, 0, stream>>>(off, sorted, asrc, adst, xw, agg);

    // ---- layer 3 ----
    fold_B3_kernel<<<(40 * 12 + 255) / 256, 256, 0, stream>>>(W3, as3, ad3, Bc);
    fold_Bf_kernel<<<(9 * 8 * 64 * 8 + 255) / 256, 256, 0, stream>>>(W3, lw3, Bf);
    feature3_kernel<<<nodeBlocks, 256, 0, stream>>>(agg, Bc, asrc, adst, zb, hp);
    z6_csr_kernel<<<waveBlocks, 256, 0, stream>>>(off, sorted, asrc, adst, hp, zb);
    zgemm_mfma_kernel<<<(NN + 127) / 128, 256, 0, stream>>>(zb, Bf, b3, lb3, out);
}